// Round 7
// baseline (5933.817 us; speedup 1.0000x reference)
//
#include <hip/hip_runtime.h>
#include <hip/hip_bf16.h>

#define N_NODES 50000
#define N_EDGES 400000
#define N_GRAPHS 64
#define HEADS 4
#define GAT_DIM 128
#define FDIM 512   // HEADS*GAT_DIM
#define NEG_SLOPE 0.2f

// ---------------- CSR build ----------------
__global__ void deg_kernel(const int* __restrict__ edst, int* __restrict__ deg) {
    int e = blockIdx.x * blockDim.x + threadIdx.x;
    if (e < N_EDGES) atomicAdd(&deg[edst[e]], 1);
}

// single block, 1024 threads: exclusive scan of deg[N_NODES] -> off[N_NODES+1]
__global__ __launch_bounds__(1024) void scan_kernel(const int* __restrict__ deg,
                                                    int* __restrict__ off) {
    __shared__ int part[1024];
    const int n = N_NODES;
    int t = threadIdx.x;
    int chunk = (n + 1023) / 1024;
    int base = t * chunk;
    int s = 0;
    for (int i = 0; i < chunk; i++) {
        int idx = base + i;
        if (idx < n) s += deg[idx];
    }
    part[t] = s;
    __syncthreads();
    for (int d = 1; d < 1024; d <<= 1) {
        int add = (t >= d) ? part[t - d] : 0;
        __syncthreads();
        part[t] += add;
        __syncthreads();
    }
    int run = part[t] - s;  // exclusive prefix of this thread's chunk
    for (int i = 0; i < chunk; i++) {
        int idx = base + i;
        if (idx < n) { off[idx] = run; run += deg[idx]; }
    }
    if (t == 0) off[n] = part[1023];
}

__global__ void fill_kernel(const int* __restrict__ esrc, const int* __restrict__ edst,
                            const int* __restrict__ off, int* __restrict__ cursor,
                            int* __restrict__ csr_src) {
    int e = blockIdx.x * blockDim.x + threadIdx.x;
    if (e >= N_EDGES) return;
    int d = edst[e];
    int pos = off[d] + atomicAdd(&cursor[d], 1);
    csr_src[pos] = esrc[e];
}

// ---------------- dual fp32 GEMM: A in LDS, B (Wl/Wr) direct from global/L2 ----------------
// R6 analysis: 4 ds_read_b128 per 64 FMA exceeds LDS b128 throughput (demand/cap=1.41,
// predicted VALUBusy cap 71% vs measured 66%). B reads are wave-redundant (16 lanes share
// an address) -> serve them from L1/L2 via the coalescer; only A stays in LDS.
#define BM 128
#define BN 64
#define BK 16
#define APAD 132
__global__ __launch_bounds__(256, 4) void gemm_dual_kernel(const float* __restrict__ A,
                                                           const float* __restrict__ Wl,
                                                           const float* __restrict__ bl,
                                                           const float* __restrict__ Wr,
                                                           const float* __restrict__ br,
                                                           float* __restrict__ xl,
                                                           float* __restrict__ xr, int M) {
    __shared__ float As[BK][APAD];  // 16 x 132 x 4B = 8.4 KB
    int bn = blockIdx.x * BN;
    int bm = blockIdx.y * BM;
    int tid = threadIdx.x;
    int tm = tid & 15, tn = tid >> 4;
    float accl[8][4] = {};
    float accr[8][4] = {};

    // A staging: 128 rows x 16 k = 512 float4 slots; 2 per thread
    const int arow[2] = {(tid * 2 + 0) >> 2, (tid * 2 + 1) >> 2};
    const int ac4[2]  = {((tid * 2 + 0) & 3) * 4, ((tid * 2 + 1) & 3) * 4};

    // thread's B column slice (same address across the 16 tm-lanes -> coalescer merge)
    const float* wlp = Wl + bn + tn * 4;
    const float* wrp = Wr + bn + tn * 4;

    float4 pa[2];
    // ---- load + stage 0 ----
#pragma unroll
    for (int i = 0; i < 2; i++) {
        int gr = bm + arow[i];
        pa[i] = (gr < M) ? *(const float4*)(A + (size_t)gr * 128 + 0 + ac4[i])
                         : make_float4(0.f, 0.f, 0.f, 0.f);
    }
#pragma unroll
    for (int i = 0; i < 2; i++) {
        As[ac4[i] + 0][arow[i]] = pa[i].x; As[ac4[i] + 1][arow[i]] = pa[i].y;
        As[ac4[i] + 2][arow[i]] = pa[i].z; As[ac4[i] + 3][arow[i]] = pa[i].w;
    }
    __syncthreads();

    for (int s = 0; s < 8; s++) {
        if (s < 7) {  // prefetch next A stage into registers
            int k0 = (s + 1) * BK;
#pragma unroll
            for (int i = 0; i < 2; i++) {
                int gr = bm + arow[i];
                pa[i] = (gr < M) ? *(const float4*)(A + (size_t)gr * 128 + k0 + ac4[i])
                                 : make_float4(0.f, 0.f, 0.f, 0.f);
            }
        }
        const int kbase = s * BK;
#pragma unroll
        for (int k = 0; k < BK; k++) {
            float4 vbl = *(const float4*)(wlp + (size_t)(kbase + k) * 512);
            float4 vbr = *(const float4*)(wrp + (size_t)(kbase + k) * 512);
            float4 alo = *(const float4*)&As[k][tm * 4];
            float4 ahi = *(const float4*)&As[k][64 + tm * 4];
            float av[8] = {alo.x, alo.y, alo.z, alo.w, ahi.x, ahi.y, ahi.z, ahi.w};
            float blv[4] = {vbl.x, vbl.y, vbl.z, vbl.w};
            float brv[4] = {vbr.x, vbr.y, vbr.z, vbr.w};
#pragma unroll
            for (int i = 0; i < 8; i++)
#pragma unroll
                for (int j = 0; j < 4; j++) {
                    accl[i][j] = fmaf(av[i], blv[j], accl[i][j]);
                    accr[i][j] = fmaf(av[i], brv[j], accr[i][j]);
                }
        }
        if (s < 7) {
            __syncthreads();
#pragma unroll
            for (int i = 0; i < 2; i++) {
                As[ac4[i] + 0][arow[i]] = pa[i].x; As[ac4[i] + 1][arow[i]] = pa[i].y;
                As[ac4[i] + 2][arow[i]] = pa[i].z; As[ac4[i] + 3][arow[i]] = pa[i].w;
            }
            __syncthreads();
        }
    }

    int gc = bn + tn * 4;
    float4 bll = *(const float4*)(bl + gc);
    float4 brr = *(const float4*)(br + gc);
#pragma unroll
    for (int i = 0; i < 8; i++) {
        int gr = bm + (i < 4 ? tm * 4 + i : 64 + tm * 4 + (i - 4));
        if (gr >= M) continue;
        float4 ol, orr;
        ol.x = accl[i][0] + bll.x; ol.y = accl[i][1] + bll.y;
        ol.z = accl[i][2] + bll.z; ol.w = accl[i][3] + bll.w;
        orr.x = accr[i][0] + brr.x; orr.y = accr[i][1] + brr.y;
        orr.z = accr[i][2] + brr.z; orr.w = accr[i][3] + brr.w;
        *(float4*)(xl + (size_t)gr * 512 + gc) = ol;
        *(float4*)(xr + (size_t)gr * 512 + gc) = orr;
    }
}

#define LK(mm) fmaf(fminf(mm, 0.f), NEG_SLOPE, fmaxf(mm, 0.f))

// ------- LAYER 0 fully fused: transform (K=3, per-edge recompute) + score + softmax
//         + aggregate + head-mean + bias + ELU. One wave per node, 2-deep x prefetch.
__global__ __launch_bounds__(256) void fused_edge0_kernel(const int* __restrict__ off,
                                                          const int* __restrict__ csr_src,
                                                          const float* __restrict__ x,
                                                          const float* __restrict__ Wl,
                                                          const float* __restrict__ bl,
                                                          const float* __restrict__ Wr,
                                                          const float* __restrict__ br,
                                                          const float* __restrict__ att,
                                                          const float* __restrict__ bias,
                                                          float* __restrict__ hout) {
    int wid = threadIdx.x >> 6;
    int lane = threadIdx.x & 63;
    int n = blockIdx.x * 4 + wid;
    if (n >= N_NODES) return;
    int s = off[n], e = off[n + 1];
    const int loff = lane * 8;
    float4 wl00 = *(const float4*)(Wl + loff),        wl01 = *(const float4*)(Wl + loff + 4);
    float4 wl10 = *(const float4*)(Wl + 512 + loff),  wl11 = *(const float4*)(Wl + 512 + loff + 4);
    float4 wl20 = *(const float4*)(Wl + 1024 + loff), wl21 = *(const float4*)(Wl + 1024 + loff + 4);
    float4 bl0  = *(const float4*)(bl + loff),        bl1  = *(const float4*)(bl + loff + 4);
    float4 at0  = *(const float4*)(att + loff),       at1  = *(const float4*)(att + loff + 4);
    float xn0 = x[n * 3 + 0], xn1 = x[n * 3 + 1], xn2 = x[n * 3 + 2];
    float4 xr0, xr1;
    {
        float4 wr00 = *(const float4*)(Wr + loff),        wr01 = *(const float4*)(Wr + loff + 4);
        float4 wr10 = *(const float4*)(Wr + 512 + loff),  wr11 = *(const float4*)(Wr + 512 + loff + 4);
        float4 wr20 = *(const float4*)(Wr + 1024 + loff), wr21 = *(const float4*)(Wr + 1024 + loff + 4);
        float4 br0  = *(const float4*)(br + loff),        br1  = *(const float4*)(br + loff + 4);
        xr0.x = fmaf(xn0, wr00.x, fmaf(xn1, wr10.x, fmaf(xn2, wr20.x, br0.x)));
        xr0.y = fmaf(xn0, wr00.y, fmaf(xn1, wr10.y, fmaf(xn2, wr20.y, br0.y)));
        xr0.z = fmaf(xn0, wr00.z, fmaf(xn1, wr10.z, fmaf(xn2, wr20.z, br0.z)));
        xr0.w = fmaf(xn0, wr00.w, fmaf(xn1, wr10.w, fmaf(xn2, wr20.w, br0.w)));
        xr1.x = fmaf(xn0, wr01.x, fmaf(xn1, wr11.x, fmaf(xn2, wr21.x, br1.x)));
        xr1.y = fmaf(xn0, wr01.y, fmaf(xn1, wr11.y, fmaf(xn2, wr21.y, br1.y)));
        xr1.z = fmaf(xn0, wr01.z, fmaf(xn1, wr11.z, fmaf(xn2, wr21.z, br1.z)));
        xr1.w = fmaf(xn0, wr01.w, fmaf(xn1, wr11.w, fmaf(xn2, wr21.w, br1.w)));
    }

    float mx = -1e30f, denom = 0.f;
    float a0 = 0.f, a1 = 0.f, a2 = 0.f, a3 = 0.f, a4 = 0.f, a5 = 0.f, a6 = 0.f, a7 = 0.f;

    float c0, c1, c2, n0, n1, n2;
    if (s < e) { int i0 = csr_src[s]; c0 = x[i0 * 3]; c1 = x[i0 * 3 + 1]; c2 = x[i0 * 3 + 2]; }
    if (s + 1 < e) { int i1 = csr_src[s + 1]; n0 = x[i1 * 3]; n1 = x[i1 * 3 + 1]; n2 = x[i1 * 3 + 2]; }
    for (int p = s; p < e; p++) {
        float t0, t1, t2;
        if (p + 2 < e) {
            int i2 = csr_src[p + 2];
            t0 = x[i2 * 3]; t1 = x[i2 * 3 + 1]; t2 = x[i2 * 3 + 2];
        }
        float4 v0, v1;
        v0.x = fmaf(c0, wl00.x, fmaf(c1, wl10.x, fmaf(c2, wl20.x, bl0.x)));
        v0.y = fmaf(c0, wl00.y, fmaf(c1, wl10.y, fmaf(c2, wl20.y, bl0.y)));
        v0.z = fmaf(c0, wl00.z, fmaf(c1, wl10.z, fmaf(c2, wl20.z, bl0.z)));
        v0.w = fmaf(c0, wl00.w, fmaf(c1, wl10.w, fmaf(c2, wl20.w, bl0.w)));
        v1.x = fmaf(c0, wl01.x, fmaf(c1, wl11.x, fmaf(c2, wl21.x, bl1.x)));
        v1.y = fmaf(c0, wl01.y, fmaf(c1, wl11.y, fmaf(c2, wl21.y, bl1.y)));
        v1.z = fmaf(c0, wl01.z, fmaf(c1, wl11.z, fmaf(c2, wl21.z, bl1.z)));
        v1.w = fmaf(c0, wl01.w, fmaf(c1, wl11.w, fmaf(c2, wl21.w, bl1.w)));
        float part;
        part = LK(v0.x + xr0.x) * at0.x;
        part = fmaf(LK(v0.y + xr0.y), at0.y, part);
        part = fmaf(LK(v0.z + xr0.z), at0.z, part);
        part = fmaf(LK(v0.w + xr0.w), at0.w, part);
        part = fmaf(LK(v1.x + xr1.x), at1.x, part);
        part = fmaf(LK(v1.y + xr1.y), at1.y, part);
        part = fmaf(LK(v1.z + xr1.z), at1.z, part);
        part = fmaf(LK(v1.w + xr1.w), at1.w, part);
        part += __shfl_xor(part, 1);
        part += __shfl_xor(part, 2);
        part += __shfl_xor(part, 4);
        part += __shfl_xor(part, 8);
        float mnew = fmaxf(mx, part);
        float scale = __expf(mx - mnew);
        float w = __expf(part - mnew);
        denom = fmaf(denom, scale, w);
        a0 = fmaf(a0, scale, w * v0.x);
        a1 = fmaf(a1, scale, w * v0.y);
        a2 = fmaf(a2, scale, w * v0.z);
        a3 = fmaf(a3, scale, w * v0.w);
        a4 = fmaf(a4, scale, w * v1.x);
        a5 = fmaf(a5, scale, w * v1.y);
        a6 = fmaf(a6, scale, w * v1.z);
        a7 = fmaf(a7, scale, w * v1.w);
        mx = mnew;
        c0 = n0; c1 = n1; c2 = n2;
        n0 = t0; n1 = t1; n2 = t2;
    }
    float inv = denom > 0.f ? 1.f / denom : 0.f;
    a0 *= inv; a1 *= inv; a2 *= inv; a3 *= inv;
    a4 *= inv; a5 *= inv; a6 *= inv; a7 *= inv;
    a0 += __shfl_xor(a0, 16); a0 += __shfl_xor(a0, 32);
    a1 += __shfl_xor(a1, 16); a1 += __shfl_xor(a1, 32);
    a2 += __shfl_xor(a2, 16); a2 += __shfl_xor(a2, 32);
    a3 += __shfl_xor(a3, 16); a3 += __shfl_xor(a3, 32);
    a4 += __shfl_xor(a4, 16); a4 += __shfl_xor(a4, 32);
    a5 += __shfl_xor(a5, 16); a5 += __shfl_xor(a5, 32);
    a6 += __shfl_xor(a6, 16); a6 += __shfl_xor(a6, 32);
    a7 += __shfl_xor(a7, 16); a7 += __shfl_xor(a7, 32);
    if (lane < 16) {
        float4 b0 = *(const float4*)(bias + lane * 8);
        float4 b1 = *(const float4*)(bias + lane * 8 + 4);
        float o[8];
        o[0] = fmaf(0.25f, a0, b0.x); o[1] = fmaf(0.25f, a1, b0.y);
        o[2] = fmaf(0.25f, a2, b0.z); o[3] = fmaf(0.25f, a3, b0.w);
        o[4] = fmaf(0.25f, a4, b1.x); o[5] = fmaf(0.25f, a5, b1.y);
        o[6] = fmaf(0.25f, a6, b1.z); o[7] = fmaf(0.25f, a7, b1.w);
#pragma unroll
        for (int j = 0; j < 8; j++) o[j] = o[j] > 0.f ? o[j] : (__expf(o[j]) - 1.f);
        *(float4*)(hout + (size_t)n * GAT_DIM + lane * 8) = make_float4(o[0], o[1], o[2], o[3]);
        *(float4*)(hout + (size_t)n * GAT_DIM + lane * 8 + 4) = make_float4(o[4], o[5], o[6], o[7]);
    }
}

// ------- layers 1/2: fused edge (xl/xr materialized), one wave per node, 2-deep prefetch ----
__global__ __launch_bounds__(256) void fused_edge_kernel(const int* __restrict__ off,
                                                         const int* __restrict__ csr_src,
                                                         const float* __restrict__ xl,
                                                         const float* __restrict__ xr,
                                                         const float* __restrict__ att,
                                                         const float* __restrict__ bias,
                                                         float* __restrict__ hout) {
    int wid = threadIdx.x >> 6;
    int lane = threadIdx.x & 63;
    int n = blockIdx.x * 4 + wid;
    if (n >= N_NODES) return;
    int s = off[n], e = off[n + 1];
    const int loff = lane * 8;
    float4 xr0 = *(const float4*)(xr + (size_t)n * FDIM + loff);
    float4 xr1 = *(const float4*)(xr + (size_t)n * FDIM + loff + 4);
    float4 at0 = *(const float4*)(att + loff);
    float4 at1 = *(const float4*)(att + loff + 4);

    float mx = -1e30f, denom = 0.f;
    float a0 = 0.f, a1 = 0.f, a2 = 0.f, a3 = 0.f, a4 = 0.f, a5 = 0.f, a6 = 0.f, a7 = 0.f;

    float4 v0, v1, w0, w1;
    if (s < e) {
        const float* b = xl + (size_t)csr_src[s] * FDIM + loff;
        v0 = *(const float4*)b; v1 = *(const float4*)(b + 4);
    }
    if (s + 1 < e) {
        const float* b = xl + (size_t)csr_src[s + 1] * FDIM + loff;
        w0 = *(const float4*)b; w1 = *(const float4*)(b + 4);
    }
    for (int p = s; p < e; p++) {
        float4 t0, t1;
        if (p + 2 < e) {
            const float* b = xl + (size_t)csr_src[p + 2] * FDIM + loff;
            t0 = *(const float4*)b; t1 = *(const float4*)(b + 4);
        }
        float part;
        part = LK(v0.x + xr0.x) * at0.x;
        part = fmaf(LK(v0.y + xr0.y), at0.y, part);
        part = fmaf(LK(v0.z + xr0.z), at0.z, part);
        part = fmaf(LK(v0.w + xr0.w), at0.w, part);
        part = fmaf(LK(v1.x + xr1.x), at1.x, part);
        part = fmaf(LK(v1.y + xr1.y), at1.y, part);
        part = fmaf(LK(v1.z + xr1.z), at1.z, part);
        part = fmaf(LK(v1.w + xr1.w), at1.w, part);
        part += __shfl_xor(part, 1);
        part += __shfl_xor(part, 2);
        part += __shfl_xor(part, 4);
        part += __shfl_xor(part, 8);
        float mnew = fmaxf(mx, part);
        float scale = __expf(mx - mnew);
        float w = __expf(part - mnew);
        denom = fmaf(denom, scale, w);
        a0 = fmaf(a0, scale, w * v0.x);
        a1 = fmaf(a1, scale, w * v0.y);
        a2 = fmaf(a2, scale, w * v0.z);
        a3 = fmaf(a3, scale, w * v0.w);
        a4 = fmaf(a4, scale, w * v1.x);
        a5 = fmaf(a5, scale, w * v1.y);
        a6 = fmaf(a6, scale, w * v1.z);
        a7 = fmaf(a7, scale, w * v1.w);
        mx = mnew;
        v0 = w0; v1 = w1;
        w0 = t0; w1 = t1;
    }
    float inv = denom > 0.f ? 1.f / denom : 0.f;
    a0 *= inv; a1 *= inv; a2 *= inv; a3 *= inv;
    a4 *= inv; a5 *= inv; a6 *= inv; a7 *= inv;
    a0 += __shfl_xor(a0, 16); a0 += __shfl_xor(a0, 32);
    a1 += __shfl_xor(a1, 16); a1 += __shfl_xor(a1, 32);
    a2 += __shfl_xor(a2, 16); a2 += __shfl_xor(a2, 32);
    a3 += __shfl_xor(a3, 16); a3 += __shfl_xor(a3, 32);
    a4 += __shfl_xor(a4, 16); a4 += __shfl_xor(a4, 32);
    a5 += __shfl_xor(a5, 16); a5 += __shfl_xor(a5, 32);
    a6 += __shfl_xor(a6, 16); a6 += __shfl_xor(a6, 32);
    a7 += __shfl_xor(a7, 16); a7 += __shfl_xor(a7, 32);
    if (lane < 16) {
        float4 b0 = *(const float4*)(bias + lane * 8);
        float4 b1 = *(const float4*)(bias + lane * 8 + 4);
        float o[8];
        o[0] = fmaf(0.25f, a0, b0.x); o[1] = fmaf(0.25f, a1, b0.y);
        o[2] = fmaf(0.25f, a2, b0.z); o[3] = fmaf(0.25f, a3, b0.w);
        o[4] = fmaf(0.25f, a4, b1.x); o[5] = fmaf(0.25f, a5, b1.y);
        o[6] = fmaf(0.25f, a6, b1.z); o[7] = fmaf(0.25f, a7, b1.w);
#pragma unroll
        for (int j = 0; j < 8; j++) o[j] = o[j] > 0.f ? o[j] : (__expf(o[j]) - 1.f);
        *(float4*)(hout + (size_t)n * GAT_DIM + lane * 8) = make_float4(o[0], o[1], o[2], o[3]);
        *(float4*)(hout + (size_t)n * GAT_DIM + lane * 8 + 4) = make_float4(o[4], o[5], o[6], o[7]);
    }
}

// ---------------- mean pool over sorted batch (double accumulation) ----------------
#define POOL_CHUNK 64
__global__ __launch_bounds__(128) void pool_kernel(const float* __restrict__ h,
                                                   const int* __restrict__ batch,
                                                   double* __restrict__ psum,
                                                   int* __restrict__ pcnt) {
    int c = threadIdx.x;  // 0..127
    int n0 = blockIdx.x * POOL_CHUNK;
    int n1 = min(n0 + POOL_CHUNK, N_NODES);
    if (n0 >= N_NODES) return;
    double acc = 0.0;
    int cur = batch[n0];
    int cnt = 0;
    for (int n = n0; n < n1; n++) {
        int g = batch[n];
        if (g != cur) {
            atomicAdd(&psum[(size_t)cur * GAT_DIM + c], acc);
            if (c == 0) atomicAdd(&pcnt[cur], cnt);
            acc = 0.0; cnt = 0; cur = g;
        }
        acc += (double)h[(size_t)n * GAT_DIM + c];
        cnt++;
    }
    atomicAdd(&psum[(size_t)cur * GAT_DIM + c], acc);
    if (c == 0) atomicAdd(&pcnt[cur], cnt);
}

// ---------------- final linear: out[64,128] = g @ linW + linb ----------------
__global__ __launch_bounds__(128) void final_kernel(const double* __restrict__ psum,
                                                    const int* __restrict__ pcnt,
                                                    const float* __restrict__ linW,
                                                    const float* __restrict__ linb,
                                                    float* __restrict__ out) {
    int g = blockIdx.x;       // 0..63
    int j = threadIdx.x;      // 0..127
    __shared__ float gv[128];
    float cnt = (float)max(pcnt[g], 1);
    gv[j] = (float)(psum[(size_t)g * 128 + j] / (double)cnt);
    __syncthreads();
    float acc = 0.f;
    for (int c = 0; c < 128; c++) acc = fmaf(gv[c], linW[c * 128 + j], acc);
    out[(size_t)g * 128 + j] = acc + linb[j];
}

extern "C" void kernel_launch(void* const* d_in, const int* in_sizes, int n_in,
                              void* d_out, int out_size, void* d_ws, size_t ws_size,
                              hipStream_t stream) {
    const float* x    = (const float*)d_in[0];
    const int* eidx   = (const int*)d_in[1];
    const int* batch  = (const int*)d_in[2];
    const float* Wl[3] = {(const float*)d_in[3],  (const float*)d_in[9],  (const float*)d_in[15]};
    const float* bl[3] = {(const float*)d_in[4],  (const float*)d_in[10], (const float*)d_in[16]};
    const float* Wr[3] = {(const float*)d_in[5],  (const float*)d_in[11], (const float*)d_in[17]};
    const float* br[3] = {(const float*)d_in[6],  (const float*)d_in[12], (const float*)d_in[18]};
    const float* att[3] = {(const float*)d_in[7], (const float*)d_in[13], (const float*)d_in[19]};
    const float* bb[3] = {(const float*)d_in[8],  (const float*)d_in[14], (const float*)d_in[20]};
    const float* linW = (const float*)d_in[21];
    const float* linb = (const float*)d_in[22];
    float* out = (float*)d_out;

    const int* esrc = eidx;
    const int* edst = eidx + N_EDGES;

    // workspace carve-up (256B aligned)
    char* p = (char*)d_ws;
    auto alloc = [&](size_t bytes) { void* r = (void*)p; p += (bytes + 255) & ~(size_t)255; return r; };
    float* xl      = (float*)alloc((size_t)N_NODES * FDIM * 4);   // 102.4 MB
    float* xr      = (float*)alloc((size_t)N_NODES * FDIM * 4);   // 102.4 MB
    float* hbuf    = (float*)alloc((size_t)N_NODES * GAT_DIM * 4);// 25.6 MB
    int*   off     = (int*)alloc((size_t)(N_NODES + 1) * 4);
    int*   csr_src = (int*)alloc((size_t)N_EDGES * 4);
    // --- contiguous zero region: deg, cursor, psum, pcnt ---
    char* zbase = p;
    int*   deg     = (int*)alloc((size_t)N_NODES * 4);
    int*   cursor  = (int*)alloc((size_t)N_NODES * 4);
    double* psum   = (double*)alloc((size_t)N_GRAPHS * GAT_DIM * 8);
    int*   pcnt    = (int*)alloc((size_t)N_GRAPHS * 4);
    size_t zbytes = (size_t)(p - zbase);

    hipMemsetAsync(zbase, 0, zbytes, stream);

    // CSR build (dst is layer-invariant)
    deg_kernel<<<(N_EDGES + 255) / 256, 256, 0, stream>>>(edst, deg);
    scan_kernel<<<1, 1024, 0, stream>>>(deg, off);
    fill_kernel<<<(N_EDGES + 255) / 256, 256, 0, stream>>>(esrc, edst, off, cursor, csr_src);

    dim3 ggrid(512 / BN, (N_NODES + BM - 1) / BM);
    const int egrid = (N_NODES + 3) / 4;  // 4 nodes (waves) per 256-thr block

    // layer 0: fully fused (K=3 transform recomputed per edge)
    fused_edge0_kernel<<<egrid, 256, 0, stream>>>(off, csr_src, x, Wl[0], bl[0], Wr[0], br[0],
                                                  att[0], bb[0], hbuf);
    // layers 1,2
    for (int l = 1; l < 3; l++) {
        gemm_dual_kernel<<<ggrid, 256, 0, stream>>>(hbuf, Wl[l], bl[l], Wr[l], br[l],
                                                    xl, xr, N_NODES);
        fused_edge_kernel<<<egrid, 256, 0, stream>>>(off, csr_src, xl, xr, att[l], bb[l], hbuf);
    }

    pool_kernel<<<(N_NODES + POOL_CHUNK - 1) / POOL_CHUNK, 128, 0, stream>>>(hbuf, batch, psum, pcnt);
    final_kernel<<<N_GRAPHS, 128, 0, stream>>>(psum, pcnt, linW, linb, out);
}

// Round 8
// 1377.813 us; speedup vs baseline: 4.3067x; 4.3067x over previous
//
#include <hip/hip_runtime.h>
#include <hip/hip_bf16.h>

#define N_NODES 50000
#define N_EDGES 400000
#define N_GRAPHS 64
#define HEADS 4
#define GAT_DIM 128
#define FDIM 512   // HEADS*GAT_DIM
#define NEG_SLOPE 0.2f

// ---------------- CSR build ----------------
__global__ void deg_kernel(const int* __restrict__ edst, int* __restrict__ deg) {
    int e = blockIdx.x * blockDim.x + threadIdx.x;
    if (e < N_EDGES) atomicAdd(&deg[edst[e]], 1);
}

// single block, 1024 threads: exclusive scan of deg[N_NODES] -> off[N_NODES+1]
__global__ __launch_bounds__(1024) void scan_kernel(const int* __restrict__ deg,
                                                    int* __restrict__ off) {
    __shared__ int part[1024];
    const int n = N_NODES;
    int t = threadIdx.x;
    int chunk = (n + 1023) / 1024;
    int base = t * chunk;
    int s = 0;
    for (int i = 0; i < chunk; i++) {
        int idx = base + i;
        if (idx < n) s += deg[idx];
    }
    part[t] = s;
    __syncthreads();
    for (int d = 1; d < 1024; d <<= 1) {
        int add = (t >= d) ? part[t - d] : 0;
        __syncthreads();
        part[t] += add;
        __syncthreads();
    }
    int run = part[t] - s;  // exclusive prefix of this thread's chunk
    for (int i = 0; i < chunk; i++) {
        int idx = base + i;
        if (idx < n) { off[idx] = run; run += deg[idx]; }
    }
    if (t == 0) off[n] = part[1023];
}

__global__ void fill_kernel(const int* __restrict__ esrc, const int* __restrict__ edst,
                            const int* __restrict__ off, int* __restrict__ cursor,
                            int* __restrict__ csr_src) {
    int e = blockIdx.x * blockDim.x + threadIdx.x;
    if (e >= N_EDGES) return;
    int d = edst[e];
    int pos = off[d] + atomicAdd(&cursor[d], 1);
    csr_src[pos] = esrc[e];
}

// ---------------- dual fp32 GEMM: wave-column decomposition ----------------
// Wave w owns cols [bn+16w, bn+16w+16) of BOTH Wl/Wr (wave-uniform -> scalar/broadcast
// B loads from L2); lane l owns row bm+l. A-tile staged to LDS ONCE (transposed,
// conflict-free b32 reads), no barriers in the k-loop. LDS demand 5.8cyc/64VALUcyc -> not binding.
// acc=32 + B temps<=32 regs; unroll 1 prevents R5/R7-style hoist spills.
#define GBM 64
#define GBN 64
__global__ __launch_bounds__(256, 4) void gemm_dual_kernel(const float* __restrict__ A,
                                                           const float* __restrict__ Wl,
                                                           const float* __restrict__ bl,
                                                           const float* __restrict__ Wr,
                                                           const float* __restrict__ br,
                                                           float* __restrict__ xl,
                                                           float* __restrict__ xr, int M) {
    __shared__ float As[128][66];  // [k][row], pad 66: lanes read consecutive banks
    int tid = threadIdx.x;
    int lane = tid & 63;
    int wid = __builtin_amdgcn_readfirstlane(tid >> 6);
    int bm = blockIdx.y * GBM;
    int bn = blockIdx.x * GBN;
    int cw = bn + wid * 16;  // this wave's 16-col group (wave-uniform)

    // ---- stage A tile 64 rows x 128 k, transposed ----
    {
        int row = tid >> 2;            // 0..63
        int c0 = (tid & 3) * 32;       // 0,32,64,96
        int gr = bm + row;
#pragma unroll
        for (int j = 0; j < 8; j++) {
            int c = c0 + j * 4;
            float4 v = (gr < M) ? *(const float4*)(A + (size_t)gr * 128 + c)
                                : make_float4(0.f, 0.f, 0.f, 0.f);
            As[c + 0][row] = v.x; As[c + 1][row] = v.y;
            As[c + 2][row] = v.z; As[c + 3][row] = v.w;
        }
    }
    __syncthreads();

    float accl[16] = {};
    float accr[16] = {};

#pragma unroll 1
    for (int k = 0; k < 128; k++) {
        const float* blp = Wl + (size_t)k * 512 + cw;
        const float* brp = Wr + (size_t)k * 512 + cw;
        float4 bL0 = *(const float4*)(blp + 0);
        float4 bL1 = *(const float4*)(blp + 4);
        float4 bL2 = *(const float4*)(blp + 8);
        float4 bL3 = *(const float4*)(blp + 12);
        float4 bR0 = *(const float4*)(brp + 0);
        float4 bR1 = *(const float4*)(brp + 4);
        float4 bR2 = *(const float4*)(brp + 8);
        float4 bR3 = *(const float4*)(brp + 12);
        float av = As[k][lane];
        accl[0]  = fmaf(av, bL0.x, accl[0]);  accl[1]  = fmaf(av, bL0.y, accl[1]);
        accl[2]  = fmaf(av, bL0.z, accl[2]);  accl[3]  = fmaf(av, bL0.w, accl[3]);
        accl[4]  = fmaf(av, bL1.x, accl[4]);  accl[5]  = fmaf(av, bL1.y, accl[5]);
        accl[6]  = fmaf(av, bL1.z, accl[6]);  accl[7]  = fmaf(av, bL1.w, accl[7]);
        accl[8]  = fmaf(av, bL2.x, accl[8]);  accl[9]  = fmaf(av, bL2.y, accl[9]);
        accl[10] = fmaf(av, bL2.z, accl[10]); accl[11] = fmaf(av, bL2.w, accl[11]);
        accl[12] = fmaf(av, bL3.x, accl[12]); accl[13] = fmaf(av, bL3.y, accl[13]);
        accl[14] = fmaf(av, bL3.z, accl[14]); accl[15] = fmaf(av, bL3.w, accl[15]);
        accr[0]  = fmaf(av, bR0.x, accr[0]);  accr[1]  = fmaf(av, bR0.y, accr[1]);
        accr[2]  = fmaf(av, bR0.z, accr[2]);  accr[3]  = fmaf(av, bR0.w, accr[3]);
        accr[4]  = fmaf(av, bR1.x, accr[4]);  accr[5]  = fmaf(av, bR1.y, accr[5]);
        accr[6]  = fmaf(av, bR1.z, accr[6]);  accr[7]  = fmaf(av, bR1.w, accr[7]);
        accr[8]  = fmaf(av, bR2.x, accr[8]);  accr[9]  = fmaf(av, bR2.y, accr[9]);
        accr[10] = fmaf(av, bR2.z, accr[10]); accr[11] = fmaf(av, bR2.w, accr[11]);
        accr[12] = fmaf(av, bR3.x, accr[12]); accr[13] = fmaf(av, bR3.y, accr[13]);
        accr[14] = fmaf(av, bR3.z, accr[14]); accr[15] = fmaf(av, bR3.w, accr[15]);
    }

    int gr = bm + lane;
    if (gr < M) {
        float4 bll0 = *(const float4*)(bl + cw + 0);
        float4 bll1 = *(const float4*)(bl + cw + 4);
        float4 bll2 = *(const float4*)(bl + cw + 8);
        float4 bll3 = *(const float4*)(bl + cw + 12);
        float4 brr0 = *(const float4*)(br + cw + 0);
        float4 brr1 = *(const float4*)(br + cw + 4);
        float4 brr2 = *(const float4*)(br + cw + 8);
        float4 brr3 = *(const float4*)(br + cw + 12);
        float* xo = xl + (size_t)gr * 512 + cw;
        float* yo = xr + (size_t)gr * 512 + cw;
        *(float4*)(xo + 0)  = make_float4(accl[0] + bll0.x, accl[1] + bll0.y, accl[2] + bll0.z, accl[3] + bll0.w);
        *(float4*)(xo + 4)  = make_float4(accl[4] + bll1.x, accl[5] + bll1.y, accl[6] + bll1.z, accl[7] + bll1.w);
        *(float4*)(xo + 8)  = make_float4(accl[8] + bll2.x, accl[9] + bll2.y, accl[10] + bll2.z, accl[11] + bll2.w);
        *(float4*)(xo + 12) = make_float4(accl[12] + bll3.x, accl[13] + bll3.y, accl[14] + bll3.z, accl[15] + bll3.w);
        *(float4*)(yo + 0)  = make_float4(accr[0] + brr0.x, accr[1] + brr0.y, accr[2] + brr0.z, accr[3] + brr0.w);
        *(float4*)(yo + 4)  = make_float4(accr[4] + brr1.x, accr[5] + brr1.y, accr[6] + brr1.z, accr[7] + brr1.w);
        *(float4*)(yo + 8)  = make_float4(accr[8] + brr2.x, accr[9] + brr2.y, accr[10] + brr2.z, accr[11] + brr2.w);
        *(float4*)(yo + 12) = make_float4(accr[12] + brr3.x, accr[13] + brr3.y, accr[14] + brr3.z, accr[15] + brr3.w);
    }
}

#define LK(mm) fmaf(fminf(mm, 0.f), NEG_SLOPE, fmaxf(mm, 0.f))

// ------- LAYER 0 fully fused: transform (K=3, per-edge recompute) + score + softmax
//         + aggregate + head-mean + bias + ELU. One wave per node, 2-deep x prefetch.
__global__ __launch_bounds__(256) void fused_edge0_kernel(const int* __restrict__ off,
                                                          const int* __restrict__ csr_src,
                                                          const float* __restrict__ x,
                                                          const float* __restrict__ Wl,
                                                          const float* __restrict__ bl,
                                                          const float* __restrict__ Wr,
                                                          const float* __restrict__ br,
                                                          const float* __restrict__ att,
                                                          const float* __restrict__ bias,
                                                          float* __restrict__ hout) {
    int wid = threadIdx.x >> 6;
    int lane = threadIdx.x & 63;
    int n = blockIdx.x * 4 + wid;
    if (n >= N_NODES) return;
    int s = off[n], e = off[n + 1];
    const int loff = lane * 8;
    float4 wl00 = *(const float4*)(Wl + loff),        wl01 = *(const float4*)(Wl + loff + 4);
    float4 wl10 = *(const float4*)(Wl + 512 + loff),  wl11 = *(const float4*)(Wl + 512 + loff + 4);
    float4 wl20 = *(const float4*)(Wl + 1024 + loff), wl21 = *(const float4*)(Wl + 1024 + loff + 4);
    float4 bl0  = *(const float4*)(bl + loff),        bl1  = *(const float4*)(bl + loff + 4);
    float4 at0  = *(const float4*)(att + loff),       at1  = *(const float4*)(att + loff + 4);
    float xn0 = x[n * 3 + 0], xn1 = x[n * 3 + 1], xn2 = x[n * 3 + 2];
    float4 xr0, xr1;
    {
        float4 wr00 = *(const float4*)(Wr + loff),        wr01 = *(const float4*)(Wr + loff + 4);
        float4 wr10 = *(const float4*)(Wr + 512 + loff),  wr11 = *(const float4*)(Wr + 512 + loff + 4);
        float4 wr20 = *(const float4*)(Wr + 1024 + loff), wr21 = *(const float4*)(Wr + 1024 + loff + 4);
        float4 br0  = *(const float4*)(br + loff),        br1  = *(const float4*)(br + loff + 4);
        xr0.x = fmaf(xn0, wr00.x, fmaf(xn1, wr10.x, fmaf(xn2, wr20.x, br0.x)));
        xr0.y = fmaf(xn0, wr00.y, fmaf(xn1, wr10.y, fmaf(xn2, wr20.y, br0.y)));
        xr0.z = fmaf(xn0, wr00.z, fmaf(xn1, wr10.z, fmaf(xn2, wr20.z, br0.z)));
        xr0.w = fmaf(xn0, wr00.w, fmaf(xn1, wr10.w, fmaf(xn2, wr20.w, br0.w)));
        xr1.x = fmaf(xn0, wr01.x, fmaf(xn1, wr11.x, fmaf(xn2, wr21.x, br1.x)));
        xr1.y = fmaf(xn0, wr01.y, fmaf(xn1, wr11.y, fmaf(xn2, wr21.y, br1.y)));
        xr1.z = fmaf(xn0, wr01.z, fmaf(xn1, wr11.z, fmaf(xn2, wr21.z, br1.z)));
        xr1.w = fmaf(xn0, wr01.w, fmaf(xn1, wr11.w, fmaf(xn2, wr21.w, br1.w)));
    }

    float mx = -1e30f, denom = 0.f;
    float a0 = 0.f, a1 = 0.f, a2 = 0.f, a3 = 0.f, a4 = 0.f, a5 = 0.f, a6 = 0.f, a7 = 0.f;

    float c0, c1, c2, n0, n1, n2;
    if (s < e) { int i0 = csr_src[s]; c0 = x[i0 * 3]; c1 = x[i0 * 3 + 1]; c2 = x[i0 * 3 + 2]; }
    if (s + 1 < e) { int i1 = csr_src[s + 1]; n0 = x[i1 * 3]; n1 = x[i1 * 3 + 1]; n2 = x[i1 * 3 + 2]; }
    for (int p = s; p < e; p++) {
        float t0, t1, t2;
        if (p + 2 < e) {
            int i2 = csr_src[p + 2];
            t0 = x[i2 * 3]; t1 = x[i2 * 3 + 1]; t2 = x[i2 * 3 + 2];
        }
        float4 v0, v1;
        v0.x = fmaf(c0, wl00.x, fmaf(c1, wl10.x, fmaf(c2, wl20.x, bl0.x)));
        v0.y = fmaf(c0, wl00.y, fmaf(c1, wl10.y, fmaf(c2, wl20.y, bl0.y)));
        v0.z = fmaf(c0, wl00.z, fmaf(c1, wl10.z, fmaf(c2, wl20.z, bl0.z)));
        v0.w = fmaf(c0, wl00.w, fmaf(c1, wl10.w, fmaf(c2, wl20.w, bl0.w)));
        v1.x = fmaf(c0, wl01.x, fmaf(c1, wl11.x, fmaf(c2, wl21.x, bl1.x)));
        v1.y = fmaf(c0, wl01.y, fmaf(c1, wl11.y, fmaf(c2, wl21.y, bl1.y)));
        v1.z = fmaf(c0, wl01.z, fmaf(c1, wl11.z, fmaf(c2, wl21.z, bl1.z)));
        v1.w = fmaf(c0, wl01.w, fmaf(c1, wl11.w, fmaf(c2, wl21.w, bl1.w)));
        float part;
        part = LK(v0.x + xr0.x) * at0.x;
        part = fmaf(LK(v0.y + xr0.y), at0.y, part);
        part = fmaf(LK(v0.z + xr0.z), at0.z, part);
        part = fmaf(LK(v0.w + xr0.w), at0.w, part);
        part = fmaf(LK(v1.x + xr1.x), at1.x, part);
        part = fmaf(LK(v1.y + xr1.y), at1.y, part);
        part = fmaf(LK(v1.z + xr1.z), at1.z, part);
        part = fmaf(LK(v1.w + xr1.w), at1.w, part);
        part += __shfl_xor(part, 1);
        part += __shfl_xor(part, 2);
        part += __shfl_xor(part, 4);
        part += __shfl_xor(part, 8);
        float mnew = fmaxf(mx, part);
        float scale = __expf(mx - mnew);
        float w = __expf(part - mnew);
        denom = fmaf(denom, scale, w);
        a0 = fmaf(a0, scale, w * v0.x);
        a1 = fmaf(a1, scale, w * v0.y);
        a2 = fmaf(a2, scale, w * v0.z);
        a3 = fmaf(a3, scale, w * v0.w);
        a4 = fmaf(a4, scale, w * v1.x);
        a5 = fmaf(a5, scale, w * v1.y);
        a6 = fmaf(a6, scale, w * v1.z);
        a7 = fmaf(a7, scale, w * v1.w);
        mx = mnew;
        c0 = n0; c1 = n1; c2 = n2;
        n0 = t0; n1 = t1; n2 = t2;
    }
    float inv = denom > 0.f ? 1.f / denom : 0.f;
    a0 *= inv; a1 *= inv; a2 *= inv; a3 *= inv;
    a4 *= inv; a5 *= inv; a6 *= inv; a7 *= inv;
    a0 += __shfl_xor(a0, 16); a0 += __shfl_xor(a0, 32);
    a1 += __shfl_xor(a1, 16); a1 += __shfl_xor(a1, 32);
    a2 += __shfl_xor(a2, 16); a2 += __shfl_xor(a2, 32);
    a3 += __shfl_xor(a3, 16); a3 += __shfl_xor(a3, 32);
    a4 += __shfl_xor(a4, 16); a4 += __shfl_xor(a4, 32);
    a5 += __shfl_xor(a5, 16); a5 += __shfl_xor(a5, 32);
    a6 += __shfl_xor(a6, 16); a6 += __shfl_xor(a6, 32);
    a7 += __shfl_xor(a7, 16); a7 += __shfl_xor(a7, 32);
    if (lane < 16) {
        float4 b0 = *(const float4*)(bias + lane * 8);
        float4 b1 = *(const float4*)(bias + lane * 8 + 4);
        float o[8];
        o[0] = fmaf(0.25f, a0, b0.x); o[1] = fmaf(0.25f, a1, b0.y);
        o[2] = fmaf(0.25f, a2, b0.z); o[3] = fmaf(0.25f, a3, b0.w);
        o[4] = fmaf(0.25f, a4, b1.x); o[5] = fmaf(0.25f, a5, b1.y);
        o[6] = fmaf(0.25f, a6, b1.z); o[7] = fmaf(0.25f, a7, b1.w);
#pragma unroll
        for (int j = 0; j < 8; j++) o[j] = o[j] > 0.f ? o[j] : (__expf(o[j]) - 1.f);
        *(float4*)(hout + (size_t)n * GAT_DIM + lane * 8) = make_float4(o[0], o[1], o[2], o[3]);
        *(float4*)(hout + (size_t)n * GAT_DIM + lane * 8 + 4) = make_float4(o[4], o[5], o[6], o[7]);
    }
}

// ------- layers 1/2: fused edge (xl/xr materialized), one wave per node, 2-deep prefetch ----
__global__ __launch_bounds__(256) void fused_edge_kernel(const int* __restrict__ off,
                                                         const int* __restrict__ csr_src,
                                                         const float* __restrict__ xl,
                                                         const float* __restrict__ xr,
                                                         const float* __restrict__ att,
                                                         const float* __restrict__ bias,
                                                         float* __restrict__ hout) {
    int wid = threadIdx.x >> 6;
    int lane = threadIdx.x & 63;
    int n = blockIdx.x * 4 + wid;
    if (n >= N_NODES) return;
    int s = off[n], e = off[n + 1];
    const int loff = lane * 8;
    float4 xr0 = *(const float4*)(xr + (size_t)n * FDIM + loff);
    float4 xr1 = *(const float4*)(xr + (size_t)n * FDIM + loff + 4);
    float4 at0 = *(const float4*)(att + loff);
    float4 at1 = *(const float4*)(att + loff + 4);

    float mx = -1e30f, denom = 0.f;
    float a0 = 0.f, a1 = 0.f, a2 = 0.f, a3 = 0.f, a4 = 0.f, a5 = 0.f, a6 = 0.f, a7 = 0.f;

    float4 v0, v1, w0, w1;
    if (s < e) {
        const float* b = xl + (size_t)csr_src[s] * FDIM + loff;
        v0 = *(const float4*)b; v1 = *(const float4*)(b + 4);
    }
    if (s + 1 < e) {
        const float* b = xl + (size_t)csr_src[s + 1] * FDIM + loff;
        w0 = *(const float4*)b; w1 = *(const float4*)(b + 4);
    }
    for (int p = s; p < e; p++) {
        float4 t0, t1;
        if (p + 2 < e) {
            const float* b = xl + (size_t)csr_src[p + 2] * FDIM + loff;
            t0 = *(const float4*)b; t1 = *(const float4*)(b + 4);
        }
        float part;
        part = LK(v0.x + xr0.x) * at0.x;
        part = fmaf(LK(v0.y + xr0.y), at0.y, part);
        part = fmaf(LK(v0.z + xr0.z), at0.z, part);
        part = fmaf(LK(v0.w + xr0.w), at0.w, part);
        part = fmaf(LK(v1.x + xr1.x), at1.x, part);
        part = fmaf(LK(v1.y + xr1.y), at1.y, part);
        part = fmaf(LK(v1.z + xr1.z), at1.z, part);
        part = fmaf(LK(v1.w + xr1.w), at1.w, part);
        part += __shfl_xor(part, 1);
        part += __shfl_xor(part, 2);
        part += __shfl_xor(part, 4);
        part += __shfl_xor(part, 8);
        float mnew = fmaxf(mx, part);
        float scale = __expf(mx - mnew);
        float w = __expf(part - mnew);
        denom = fmaf(denom, scale, w);
        a0 = fmaf(a0, scale, w * v0.x);
        a1 = fmaf(a1, scale, w * v0.y);
        a2 = fmaf(a2, scale, w * v0.z);
        a3 = fmaf(a3, scale, w * v0.w);
        a4 = fmaf(a4, scale, w * v1.x);
        a5 = fmaf(a5, scale, w * v1.y);
        a6 = fmaf(a6, scale, w * v1.z);
        a7 = fmaf(a7, scale, w * v1.w);
        mx = mnew;
        v0 = w0; v1 = w1;
        w0 = t0; w1 = t1;
    }
    float inv = denom > 0.f ? 1.f / denom : 0.f;
    a0 *= inv; a1 *= inv; a2 *= inv; a3 *= inv;
    a4 *= inv; a5 *= inv; a6 *= inv; a7 *= inv;
    a0 += __shfl_xor(a0, 16); a0 += __shfl_xor(a0, 32);
    a1 += __shfl_xor(a1, 16); a1 += __shfl_xor(a1, 32);
    a2 += __shfl_xor(a2, 16); a2 += __shfl_xor(a2, 32);
    a3 += __shfl_xor(a3, 16); a3 += __shfl_xor(a3, 32);
    a4 += __shfl_xor(a4, 16); a4 += __shfl_xor(a4, 32);
    a5 += __shfl_xor(a5, 16); a5 += __shfl_xor(a5, 32);
    a6 += __shfl_xor(a6, 16); a6 += __shfl_xor(a6, 32);
    a7 += __shfl_xor(a7, 16); a7 += __shfl_xor(a7, 32);
    if (lane < 16) {
        float4 b0 = *(const float4*)(bias + lane * 8);
        float4 b1 = *(const float4*)(bias + lane * 8 + 4);
        float o[8];
        o[0] = fmaf(0.25f, a0, b0.x); o[1] = fmaf(0.25f, a1, b0.y);
        o[2] = fmaf(0.25f, a2, b0.z); o[3] = fmaf(0.25f, a3, b0.w);
        o[4] = fmaf(0.25f, a4, b1.x); o[5] = fmaf(0.25f, a5, b1.y);
        o[6] = fmaf(0.25f, a6, b1.z); o[7] = fmaf(0.25f, a7, b1.w);
#pragma unroll
        for (int j = 0; j < 8; j++) o[j] = o[j] > 0.f ? o[j] : (__expf(o[j]) - 1.f);
        *(float4*)(hout + (size_t)n * GAT_DIM + lane * 8) = make_float4(o[0], o[1], o[2], o[3]);
        *(float4*)(hout + (size_t)n * GAT_DIM + lane * 8 + 4) = make_float4(o[4], o[5], o[6], o[7]);
    }
}

// ---------------- mean pool over sorted batch (double accumulation) ----------------
#define POOL_CHUNK 64
__global__ __launch_bounds__(128) void pool_kernel(const float* __restrict__ h,
                                                   const int* __restrict__ batch,
                                                   double* __restrict__ psum,
                                                   int* __restrict__ pcnt) {
    int c = threadIdx.x;  // 0..127
    int n0 = blockIdx.x * POOL_CHUNK;
    int n1 = min(n0 + POOL_CHUNK, N_NODES);
    if (n0 >= N_NODES) return;
    double acc = 0.0;
    int cur = batch[n0];
    int cnt = 0;
    for (int n = n0; n < n1; n++) {
        int g = batch[n];
        if (g != cur) {
            atomicAdd(&psum[(size_t)cur * GAT_DIM + c], acc);
            if (c == 0) atomicAdd(&pcnt[cur], cnt);
            acc = 0.0; cnt = 0; cur = g;
        }
        acc += (double)h[(size_t)n * GAT_DIM + c];
        cnt++;
    }
    atomicAdd(&psum[(size_t)cur * GAT_DIM + c], acc);
    if (c == 0) atomicAdd(&pcnt[cur], cnt);
}

// ---------------- final linear: out[64,128] = g @ linW + linb ----------------
__global__ __launch_bounds__(128) void final_kernel(const double* __restrict__ psum,
                                                    const int* __restrict__ pcnt,
                                                    const float* __restrict__ linW,
                                                    const float* __restrict__ linb,
                                                    float* __restrict__ out) {
    int g = blockIdx.x;       // 0..63
    int j = threadIdx.x;      // 0..127
    __shared__ float gv[128];
    float cnt = (float)max(pcnt[g], 1);
    gv[j] = (float)(psum[(size_t)g * 128 + j] / (double)cnt);
    __syncthreads();
    float acc = 0.f;
    for (int c = 0; c < 128; c++) acc = fmaf(gv[c], linW[c * 128 + j], acc);
    out[(size_t)g * 128 + j] = acc + linb[j];
}

extern "C" void kernel_launch(void* const* d_in, const int* in_sizes, int n_in,
                              void* d_out, int out_size, void* d_ws, size_t ws_size,
                              hipStream_t stream) {
    const float* x    = (const float*)d_in[0];
    const int* eidx   = (const int*)d_in[1];
    const int* batch  = (const int*)d_in[2];
    const float* Wl[3] = {(const float*)d_in[3],  (const float*)d_in[9],  (const float*)d_in[15]};
    const float* bl[3] = {(const float*)d_in[4],  (const float*)d_in[10], (const float*)d_in[16]};
    const float* Wr[3] = {(const float*)d_in[5],  (const float*)d_in[11], (const float*)d_in[17]};
    const float* br[3] = {(const float*)d_in[6],  (const float*)d_in[12], (const float*)d_in[18]};
    const float* att[3] = {(const float*)d_in[7], (const float*)d_in[13], (const float*)d_in[19]};
    const float* bb[3] = {(const float*)d_in[8],  (const float*)d_in[14], (const float*)d_in[20]};
    const float* linW = (const float*)d_in[21];
    const float* linb = (const float*)d_in[22];
    float* out = (float*)d_out;

    const int* esrc = eidx;
    const int* edst = eidx + N_EDGES;

    // workspace carve-up (256B aligned)
    char* p = (char*)d_ws;
    auto alloc = [&](size_t bytes) { void* r = (void*)p; p += (bytes + 255) & ~(size_t)255; return r; };
    float* xl      = (float*)alloc((size_t)N_NODES * FDIM * 4);   // 102.4 MB
    float* xr      = (float*)alloc((size_t)N_NODES * FDIM * 4);   // 102.4 MB
    float* hbuf    = (float*)alloc((size_t)N_NODES * GAT_DIM * 4);// 25.6 MB
    int*   off     = (int*)alloc((size_t)(N_NODES + 1) * 4);
    int*   csr_src = (int*)alloc((size_t)N_EDGES * 4);
    // --- contiguous zero region: deg, cursor, psum, pcnt ---
    char* zbase = p;
    int*   deg     = (int*)alloc((size_t)N_NODES * 4);
    int*   cursor  = (int*)alloc((size_t)N_NODES * 4);
    double* psum   = (double*)alloc((size_t)N_GRAPHS * GAT_DIM * 8);
    int*   pcnt    = (int*)alloc((size_t)N_GRAPHS * 4);
    size_t zbytes = (size_t)(p - zbase);

    hipMemsetAsync(zbase, 0, zbytes, stream);

    // CSR build (dst is layer-invariant)
    deg_kernel<<<(N_EDGES + 255) / 256, 256, 0, stream>>>(edst, deg);
    scan_kernel<<<1, 1024, 0, stream>>>(deg, off);
    fill_kernel<<<(N_EDGES + 255) / 256, 256, 0, stream>>>(esrc, edst, off, cursor, csr_src);

    dim3 ggrid(512 / GBN, (N_NODES + GBM - 1) / GBM);
    const int egrid = (N_NODES + 3) / 4;  // 4 nodes (waves) per 256-thr block

    // layer 0: fully fused (K=3 transform recomputed per edge)
    fused_edge0_kernel<<<egrid, 256, 0, stream>>>(off, csr_src, x, Wl[0], bl[0], Wr[0], br[0],
                                                  att[0], bb[0], hbuf);
    // layers 1,2
    for (int l = 1; l < 3; l++) {
        gemm_dual_kernel<<<ggrid, 256, 0, stream>>>(hbuf, Wl[l], bl[l], Wr[l], br[l],
                                                    xl, xr, N_NODES);
        fused_edge_kernel<<<egrid, 256, 0, stream>>>(off, csr_src, xl, xr, att[l], bb[l], hbuf);
    }

    pool_kernel<<<(N_NODES + POOL_CHUNK - 1) / POOL_CHUNK, 128, 0, stream>>>(hbuf, batch, psum, pcnt);
    final_kernel<<<N_GRAPHS, 128, 0, stream>>>(psum, pcnt, linW, linb, out);
}

// Round 9
// 969.482 us; speedup vs baseline: 6.1206x; 1.4212x over previous
//
#include <hip/hip_runtime.h>
#include <hip/hip_bf16.h>

#define N_NODES 50000
#define N_EDGES 400000
#define N_GRAPHS 64
#define HEADS 4
#define GAT_DIM 128
#define FDIM 512   // HEADS*GAT_DIM
#define NEG_SLOPE 0.2f

// ---------------- CSR build ----------------
__global__ void deg_kernel(const int* __restrict__ edst, int* __restrict__ deg) {
    int e = blockIdx.x * blockDim.x + threadIdx.x;
    if (e < N_EDGES) atomicAdd(&deg[edst[e]], 1);
}

// single block, 1024 threads: exclusive scan of deg[N_NODES] -> off[N_NODES+1]
__global__ __launch_bounds__(1024) void scan_kernel(const int* __restrict__ deg,
                                                    int* __restrict__ off) {
    __shared__ int part[1024];
    const int n = N_NODES;
    int t = threadIdx.x;
    int chunk = (n + 1023) / 1024;
    int base = t * chunk;
    int s = 0;
    for (int i = 0; i < chunk; i++) {
        int idx = base + i;
        if (idx < n) s += deg[idx];
    }
    part[t] = s;
    __syncthreads();
    for (int d = 1; d < 1024; d <<= 1) {
        int add = (t >= d) ? part[t - d] : 0;
        __syncthreads();
        part[t] += add;
        __syncthreads();
    }
    int run = part[t] - s;  // exclusive prefix of this thread's chunk
    for (int i = 0; i < chunk; i++) {
        int idx = base + i;
        if (idx < n) { off[idx] = run; run += deg[idx]; }
    }
    if (t == 0) off[n] = part[1023];
}

__global__ void fill_kernel(const int* __restrict__ esrc, const int* __restrict__ edst,
                            const int* __restrict__ off, int* __restrict__ cursor,
                            int* __restrict__ csr_src) {
    int e = blockIdx.x * blockDim.x + threadIdx.x;
    if (e >= N_EDGES) return;
    int d = edst[e];
    int pos = off[d] + atomicAdd(&cursor[d], 1);
    csr_src[pos] = esrc[e];
}

// ---------------- dual fp32 GEMM (R6 champion: BK=16, single-buffer LDS + reg prefetch) ----
// Measured R6: 170us, VALUBusy 66%, VGPR 64 — LDS-issue-bound local optimum.
// DO NOT: (256,8) -> spills acc (R5, 20GB scratch); B-from-global unrolled -> hoist spills
// (R7, 10GB); wave-column + unroll 1 -> exposed L2 latency, 24% VALU (R8).
#define BM 128
#define BN 64
#define BK 16
#define APAD 132
#define BPAD 68
__global__ __launch_bounds__(256, 4) void gemm_dual_kernel(const float* __restrict__ A,
                                                           const float* __restrict__ Wl,
                                                           const float* __restrict__ bl,
                                                           const float* __restrict__ Wr,
                                                           const float* __restrict__ br,
                                                           float* __restrict__ xl,
                                                           float* __restrict__ xr, int M) {
    __shared__ float As[BK][APAD];
    __shared__ float Bsl[BK][BPAD];
    __shared__ float Bsr[BK][BPAD];
    int bn = blockIdx.x * BN;
    int bm = blockIdx.y * BM;
    int tid = threadIdx.x;
    int tm = tid & 15, tn = tid >> 4;
    float accl[8][4] = {};
    float accr[8][4] = {};

    const int arow[2] = {(tid * 2 + 0) >> 2, (tid * 2 + 1) >> 2};
    const int ac4[2]  = {((tid * 2 + 0) & 3) * 4, ((tid * 2 + 1) & 3) * 4};
    const int brow = tid >> 4;
    const int bc4  = (tid & 15) * 4;

    float4 pa[2], pbl, pbr;

#pragma unroll
    for (int i = 0; i < 2; i++) {
        int gr = bm + arow[i];
        pa[i] = (gr < M) ? *(const float4*)(A + (size_t)gr * 128 + 0 + ac4[i])
                         : make_float4(0.f, 0.f, 0.f, 0.f);
    }
    pbl = *(const float4*)(Wl + (size_t)(0 + brow) * 512 + bn + bc4);
    pbr = *(const float4*)(Wr + (size_t)(0 + brow) * 512 + bn + bc4);
#pragma unroll
    for (int i = 0; i < 2; i++) {
        As[ac4[i] + 0][arow[i]] = pa[i].x; As[ac4[i] + 1][arow[i]] = pa[i].y;
        As[ac4[i] + 2][arow[i]] = pa[i].z; As[ac4[i] + 3][arow[i]] = pa[i].w;
    }
    *(float4*)&Bsl[brow][bc4] = pbl;
    *(float4*)&Bsr[brow][bc4] = pbr;
    __syncthreads();

    for (int s = 0; s < 8; s++) {
        if (s < 7) {
            int k0 = (s + 1) * BK;
#pragma unroll
            for (int i = 0; i < 2; i++) {
                int gr = bm + arow[i];
                pa[i] = (gr < M) ? *(const float4*)(A + (size_t)gr * 128 + k0 + ac4[i])
                                 : make_float4(0.f, 0.f, 0.f, 0.f);
            }
            pbl = *(const float4*)(Wl + (size_t)(k0 + brow) * 512 + bn + bc4);
            pbr = *(const float4*)(Wr + (size_t)(k0 + brow) * 512 + bn + bc4);
        }
#pragma unroll 4
        for (int k = 0; k < BK; k++) {
            float4 alo = *(const float4*)&As[k][tm * 4];
            float4 ahi = *(const float4*)&As[k][64 + tm * 4];
            float4 vbl = *(const float4*)&Bsl[k][tn * 4];
            float4 vbr = *(const float4*)&Bsr[k][tn * 4];
            float av[8] = {alo.x, alo.y, alo.z, alo.w, ahi.x, ahi.y, ahi.z, ahi.w};
            float blv[4] = {vbl.x, vbl.y, vbl.z, vbl.w};
            float brv[4] = {vbr.x, vbr.y, vbr.z, vbr.w};
#pragma unroll
            for (int i = 0; i < 8; i++)
#pragma unroll
                for (int j = 0; j < 4; j++) {
                    accl[i][j] = fmaf(av[i], blv[j], accl[i][j]);
                    accr[i][j] = fmaf(av[i], brv[j], accr[i][j]);
                }
        }
        if (s < 7) {
            __syncthreads();
#pragma unroll
            for (int i = 0; i < 2; i++) {
                As[ac4[i] + 0][arow[i]] = pa[i].x; As[ac4[i] + 1][arow[i]] = pa[i].y;
                As[ac4[i] + 2][arow[i]] = pa[i].z; As[ac4[i] + 3][arow[i]] = pa[i].w;
            }
            *(float4*)&Bsl[brow][bc4] = pbl;
            *(float4*)&Bsr[brow][bc4] = pbr;
            __syncthreads();
        }
    }

    int gc = bn + tn * 4;
    float4 bll = *(const float4*)(bl + gc);
    float4 brr = *(const float4*)(br + gc);
#pragma unroll
    for (int i = 0; i < 8; i++) {
        int gr = bm + (i < 4 ? tm * 4 + i : 64 + tm * 4 + (i - 4));
        if (gr >= M) continue;
        float4 ol, orr;
        ol.x = accl[i][0] + bll.x; ol.y = accl[i][1] + bll.y;
        ol.z = accl[i][2] + bll.z; ol.w = accl[i][3] + bll.w;
        orr.x = accr[i][0] + brr.x; orr.y = accr[i][1] + brr.y;
        orr.z = accr[i][2] + brr.z; orr.w = accr[i][3] + brr.w;
        *(float4*)(xl + (size_t)gr * 512 + gc) = ol;
        *(float4*)(xr + (size_t)gr * 512 + gc) = orr;
    }
}

#define LK(mm) fmaf(fminf(mm, 0.f), NEG_SLOPE, fmaxf(mm, 0.f))

// ------- LAYER 0 fully fused: transform (K=3, per-edge recompute) + score + softmax
//         + aggregate + head-mean + bias + ELU. One wave per node, 2-deep x prefetch.
__global__ __launch_bounds__(256) void fused_edge0_kernel(const int* __restrict__ off,
                                                          const int* __restrict__ csr_src,
                                                          const float* __restrict__ x,
                                                          const float* __restrict__ Wl,
                                                          const float* __restrict__ bl,
                                                          const float* __restrict__ Wr,
                                                          const float* __restrict__ br,
                                                          const float* __restrict__ att,
                                                          const float* __restrict__ bias,
                                                          float* __restrict__ hout) {
    int wid = threadIdx.x >> 6;
    int lane = threadIdx.x & 63;
    int n = blockIdx.x * 4 + wid;
    if (n >= N_NODES) return;
    int s = off[n], e = off[n + 1];
    const int loff = lane * 8;
    float4 wl00 = *(const float4*)(Wl + loff),        wl01 = *(const float4*)(Wl + loff + 4);
    float4 wl10 = *(const float4*)(Wl + 512 + loff),  wl11 = *(const float4*)(Wl + 512 + loff + 4);
    float4 wl20 = *(const float4*)(Wl + 1024 + loff), wl21 = *(const float4*)(Wl + 1024 + loff + 4);
    float4 bl0  = *(const float4*)(bl + loff),        bl1  = *(const float4*)(bl + loff + 4);
    float4 at0  = *(const float4*)(att + loff),       at1  = *(const float4*)(att + loff + 4);
    float xn0 = x[n * 3 + 0], xn1 = x[n * 3 + 1], xn2 = x[n * 3 + 2];
    float4 xr0, xr1;
    {
        float4 wr00 = *(const float4*)(Wr + loff),        wr01 = *(const float4*)(Wr + loff + 4);
        float4 wr10 = *(const float4*)(Wr + 512 + loff),  wr11 = *(const float4*)(Wr + 512 + loff + 4);
        float4 wr20 = *(const float4*)(Wr + 1024 + loff), wr21 = *(const float4*)(Wr + 1024 + loff + 4);
        float4 br0  = *(const float4*)(br + loff),        br1  = *(const float4*)(br + loff + 4);
        xr0.x = fmaf(xn0, wr00.x, fmaf(xn1, wr10.x, fmaf(xn2, wr20.x, br0.x)));
        xr0.y = fmaf(xn0, wr00.y, fmaf(xn1, wr10.y, fmaf(xn2, wr20.y, br0.y)));
        xr0.z = fmaf(xn0, wr00.z, fmaf(xn1, wr10.z, fmaf(xn2, wr20.z, br0.z)));
        xr0.w = fmaf(xn0, wr00.w, fmaf(xn1, wr10.w, fmaf(xn2, wr20.w, br0.w)));
        xr1.x = fmaf(xn0, wr01.x, fmaf(xn1, wr11.x, fmaf(xn2, wr21.x, br1.x)));
        xr1.y = fmaf(xn0, wr01.y, fmaf(xn1, wr11.y, fmaf(xn2, wr21.y, br1.y)));
        xr1.z = fmaf(xn0, wr01.z, fmaf(xn1, wr11.z, fmaf(xn2, wr21.z, br1.z)));
        xr1.w = fmaf(xn0, wr01.w, fmaf(xn1, wr11.w, fmaf(xn2, wr21.w, br1.w)));
    }

    float mx = -1e30f, denom = 0.f;
    float a0 = 0.f, a1 = 0.f, a2 = 0.f, a3 = 0.f, a4 = 0.f, a5 = 0.f, a6 = 0.f, a7 = 0.f;

    float c0, c1, c2, n0, n1, n2;
    if (s < e) { int i0 = csr_src[s]; c0 = x[i0 * 3]; c1 = x[i0 * 3 + 1]; c2 = x[i0 * 3 + 2]; }
    if (s + 1 < e) { int i1 = csr_src[s + 1]; n0 = x[i1 * 3]; n1 = x[i1 * 3 + 1]; n2 = x[i1 * 3 + 2]; }
    for (int p = s; p < e; p++) {
        float t0, t1, t2;
        if (p + 2 < e) {
            int i2 = csr_src[p + 2];
            t0 = x[i2 * 3]; t1 = x[i2 * 3 + 1]; t2 = x[i2 * 3 + 2];
        }
        float4 v0, v1;
        v0.x = fmaf(c0, wl00.x, fmaf(c1, wl10.x, fmaf(c2, wl20.x, bl0.x)));
        v0.y = fmaf(c0, wl00.y, fmaf(c1, wl10.y, fmaf(c2, wl20.y, bl0.y)));
        v0.z = fmaf(c0, wl00.z, fmaf(c1, wl10.z, fmaf(c2, wl20.z, bl0.z)));
        v0.w = fmaf(c0, wl00.w, fmaf(c1, wl10.w, fmaf(c2, wl20.w, bl0.w)));
        v1.x = fmaf(c0, wl01.x, fmaf(c1, wl11.x, fmaf(c2, wl21.x, bl1.x)));
        v1.y = fmaf(c0, wl01.y, fmaf(c1, wl11.y, fmaf(c2, wl21.y, bl1.y)));
        v1.z = fmaf(c0, wl01.z, fmaf(c1, wl11.z, fmaf(c2, wl21.z, bl1.z)));
        v1.w = fmaf(c0, wl01.w, fmaf(c1, wl11.w, fmaf(c2, wl21.w, bl1.w)));
        float part;
        part = LK(v0.x + xr0.x) * at0.x;
        part = fmaf(LK(v0.y + xr0.y), at0.y, part);
        part = fmaf(LK(v0.z + xr0.z), at0.z, part);
        part = fmaf(LK(v0.w + xr0.w), at0.w, part);
        part = fmaf(LK(v1.x + xr1.x), at1.x, part);
        part = fmaf(LK(v1.y + xr1.y), at1.y, part);
        part = fmaf(LK(v1.z + xr1.z), at1.z, part);
        part = fmaf(LK(v1.w + xr1.w), at1.w, part);
        part += __shfl_xor(part, 1);
        part += __shfl_xor(part, 2);
        part += __shfl_xor(part, 4);
        part += __shfl_xor(part, 8);
        float mnew = fmaxf(mx, part);
        float scale = __expf(mx - mnew);
        float w = __expf(part - mnew);
        denom = fmaf(denom, scale, w);
        a0 = fmaf(a0, scale, w * v0.x);
        a1 = fmaf(a1, scale, w * v0.y);
        a2 = fmaf(a2, scale, w * v0.z);
        a3 = fmaf(a3, scale, w * v0.w);
        a4 = fmaf(a4, scale, w * v1.x);
        a5 = fmaf(a5, scale, w * v1.y);
        a6 = fmaf(a6, scale, w * v1.z);
        a7 = fmaf(a7, scale, w * v1.w);
        mx = mnew;
        c0 = n0; c1 = n1; c2 = n2;
        n0 = t0; n1 = t1; n2 = t2;
    }
    float inv = denom > 0.f ? 1.f / denom : 0.f;
    a0 *= inv; a1 *= inv; a2 *= inv; a3 *= inv;
    a4 *= inv; a5 *= inv; a6 *= inv; a7 *= inv;
    a0 += __shfl_xor(a0, 16); a0 += __shfl_xor(a0, 32);
    a1 += __shfl_xor(a1, 16); a1 += __shfl_xor(a1, 32);
    a2 += __shfl_xor(a2, 16); a2 += __shfl_xor(a2, 32);
    a3 += __shfl_xor(a3, 16); a3 += __shfl_xor(a3, 32);
    a4 += __shfl_xor(a4, 16); a4 += __shfl_xor(a4, 32);
    a5 += __shfl_xor(a5, 16); a5 += __shfl_xor(a5, 32);
    a6 += __shfl_xor(a6, 16); a6 += __shfl_xor(a6, 32);
    a7 += __shfl_xor(a7, 16); a7 += __shfl_xor(a7, 32);
    if (lane < 16) {
        float4 b0 = *(const float4*)(bias + lane * 8);
        float4 b1 = *(const float4*)(bias + lane * 8 + 4);
        float o[8];
        o[0] = fmaf(0.25f, a0, b0.x); o[1] = fmaf(0.25f, a1, b0.y);
        o[2] = fmaf(0.25f, a2, b0.z); o[3] = fmaf(0.25f, a3, b0.w);
        o[4] = fmaf(0.25f, a4, b1.x); o[5] = fmaf(0.25f, a5, b1.y);
        o[6] = fmaf(0.25f, a6, b1.z); o[7] = fmaf(0.25f, a7, b1.w);
#pragma unroll
        for (int j = 0; j < 8; j++) o[j] = o[j] > 0.f ? o[j] : (__expf(o[j]) - 1.f);
        *(float4*)(hout + (size_t)n * GAT_DIM + lane * 8) = make_float4(o[0], o[1], o[2], o[3]);
        *(float4*)(hout + (size_t)n * GAT_DIM + lane * 8 + 4) = make_float4(o[4], o[5], o[6], o[7]);
    }
}

// ------- layers 1/2: fused edge, TWO waves per node (parity-split edge list, online-softmax
//         state merged in LDS). 4 gathers in flight per node; iterations halve vs R6.
__global__ __launch_bounds__(256) void fused_edge_kernel(const int* __restrict__ off,
                                                         const int* __restrict__ csr_src,
                                                         const float* __restrict__ xl,
                                                         const float* __restrict__ xr,
                                                         const float* __restrict__ att,
                                                         const float* __restrict__ bias,
                                                         float* __restrict__ hout) {
    __shared__ float shacc[2][512];
    __shared__ float shmd[2][2];   // [pair][0]=m, [1]=denom from helper wave
    int wid = threadIdx.x >> 6;    // 0..3
    int lane = threadIdx.x & 63;
    int pair = wid >> 1;           // node slot within block
    int half = wid & 1;            // 0 = combiner wave, 1 = helper wave
    int n = blockIdx.x * 2 + pair;
    bool active = (n < N_NODES);
    int s = 0, e = 0;
    if (active) { s = off[n]; e = off[n + 1]; }
    const int loff = lane * 8;
    float4 xr0, xr1;
    if (active) {
        xr0 = *(const float4*)(xr + (size_t)n * FDIM + loff);
        xr1 = *(const float4*)(xr + (size_t)n * FDIM + loff + 4);
    }
    float4 at0 = *(const float4*)(att + loff);
    float4 at1 = *(const float4*)(att + loff + 4);

    float mx = -1e30f, denom = 0.f;
    float a0 = 0.f, a1 = 0.f, a2 = 0.f, a3 = 0.f, a4 = 0.f, a5 = 0.f, a6 = 0.f, a7 = 0.f;

    int p0 = s + half;  // this wave's parity stream: p0, p0+2, ...
    float4 v0, v1, w0, w1;
    if (active && p0 < e) {
        const float* b = xl + (size_t)csr_src[p0] * FDIM + loff;
        v0 = *(const float4*)b; v1 = *(const float4*)(b + 4);
    }
    if (active && p0 + 2 < e) {
        const float* b = xl + (size_t)csr_src[p0 + 2] * FDIM + loff;
        w0 = *(const float4*)b; w1 = *(const float4*)(b + 4);
    }
    if (active) {
        for (int p = p0; p < e; p += 2) {
            float4 t0, t1;
            if (p + 4 < e) {
                const float* b = xl + (size_t)csr_src[p + 4] * FDIM + loff;
                t0 = *(const float4*)b; t1 = *(const float4*)(b + 4);
            }
            float part;
            part = LK(v0.x + xr0.x) * at0.x;
            part = fmaf(LK(v0.y + xr0.y), at0.y, part);
            part = fmaf(LK(v0.z + xr0.z), at0.z, part);
            part = fmaf(LK(v0.w + xr0.w), at0.w, part);
            part = fmaf(LK(v1.x + xr1.x), at1.x, part);
            part = fmaf(LK(v1.y + xr1.y), at1.y, part);
            part = fmaf(LK(v1.z + xr1.z), at1.z, part);
            part = fmaf(LK(v1.w + xr1.w), at1.w, part);
            part += __shfl_xor(part, 1);
            part += __shfl_xor(part, 2);
            part += __shfl_xor(part, 4);
            part += __shfl_xor(part, 8);
            float mnew = fmaxf(mx, part);
            float scale = __expf(mx - mnew);
            float w = __expf(part - mnew);
            denom = fmaf(denom, scale, w);
            a0 = fmaf(a0, scale, w * v0.x);
            a1 = fmaf(a1, scale, w * v0.y);
            a2 = fmaf(a2, scale, w * v0.z);
            a3 = fmaf(a3, scale, w * v0.w);
            a4 = fmaf(a4, scale, w * v1.x);
            a5 = fmaf(a5, scale, w * v1.y);
            a6 = fmaf(a6, scale, w * v1.z);
            a7 = fmaf(a7, scale, w * v1.w);
            mx = mnew;
            v0 = w0; v1 = w1;
            w0 = t0; w1 = t1;
        }
    }
    // helper wave publishes its state (m/denom are uniform within each 16-lane head group;
    // store per-head scalars via lane 0 of each group is unnecessary — shmd holds per-head
    // values implicitly since mx is head-dependent! Store per-lane to be safe.)
    if (half == 1) {
        shacc[pair][loff + 0] = a0; shacc[pair][loff + 1] = a1;
        shacc[pair][loff + 2] = a2; shacc[pair][loff + 3] = a3;
        shacc[pair][loff + 4] = a4; shacc[pair][loff + 5] = a5;
        shacc[pair][loff + 6] = a6; shacc[pair][loff + 7] = a7;
        // m/denom differ per head (16-lane group); reuse shacc trick: stash in shmd per pair
        // via 4 head slots — but lanes within a head group agree, so write lane%16==0 slots.
        if ((lane & 15) == 0) {
            // head index = lane>>4; pack m and denom into shmd rows
            ((float*)shmd)[pair * 2 * 4 + 0 + (lane >> 4)] = mx;      // m[head]
            ((float*)shmd)[pair * 2 * 4 + 4 + (lane >> 4)] = denom;   // d[head] (abuse layout)
        }
    }
    __syncthreads();
    if (half == 0 && active) {
        int h = lane >> 4;
        float mB = ((float*)shmd)[pair * 2 * 4 + 0 + h];
        float dB = ((float*)shmd)[pair * 2 * 4 + 4 + h];
        float m = fmaxf(mx, mB);
        float sA = __expf(mx - m);
        float sB = __expf(mB - m);
        float d = denom * sA + dB * sB;
        a0 = a0 * sA + shacc[pair][loff + 0] * sB;
        a1 = a1 * sA + shacc[pair][loff + 1] * sB;
        a2 = a2 * sA + shacc[pair][loff + 2] * sB;
        a3 = a3 * sA + shacc[pair][loff + 3] * sB;
        a4 = a4 * sA + shacc[pair][loff + 4] * sB;
        a5 = a5 * sA + shacc[pair][loff + 5] * sB;
        a6 = a6 * sA + shacc[pair][loff + 6] * sB;
        a7 = a7 * sA + shacc[pair][loff + 7] * sB;
        float inv = d > 0.f ? 1.f / d : 0.f;
        a0 *= inv; a1 *= inv; a2 *= inv; a3 *= inv;
        a4 *= inv; a5 *= inv; a6 *= inv; a7 *= inv;
        a0 += __shfl_xor(a0, 16); a0 += __shfl_xor(a0, 32);
        a1 += __shfl_xor(a1, 16); a1 += __shfl_xor(a1, 32);
        a2 += __shfl_xor(a2, 16); a2 += __shfl_xor(a2, 32);
        a3 += __shfl_xor(a3, 16); a3 += __shfl_xor(a3, 32);
        a4 += __shfl_xor(a4, 16); a4 += __shfl_xor(a4, 32);
        a5 += __shfl_xor(a5, 16); a5 += __shfl_xor(a5, 32);
        a6 += __shfl_xor(a6, 16); a6 += __shfl_xor(a6, 32);
        a7 += __shfl_xor(a7, 16); a7 += __shfl_xor(a7, 32);
        if (lane < 16) {
            float4 b0 = *(const float4*)(bias + lane * 8);
            float4 b1 = *(const float4*)(bias + lane * 8 + 4);
            float o[8];
            o[0] = fmaf(0.25f, a0, b0.x); o[1] = fmaf(0.25f, a1, b0.y);
            o[2] = fmaf(0.25f, a2, b0.z); o[3] = fmaf(0.25f, a3, b0.w);
            o[4] = fmaf(0.25f, a4, b1.x); o[5] = fmaf(0.25f, a5, b1.y);
            o[6] = fmaf(0.25f, a6, b1.z); o[7] = fmaf(0.25f, a7, b1.w);
#pragma unroll
            for (int j = 0; j < 8; j++) o[j] = o[j] > 0.f ? o[j] : (__expf(o[j]) - 1.f);
            *(float4*)(hout + (size_t)n * GAT_DIM + lane * 8) = make_float4(o[0], o[1], o[2], o[3]);
            *(float4*)(hout + (size_t)n * GAT_DIM + lane * 8 + 4) = make_float4(o[4], o[5], o[6], o[7]);
        }
    }
}

// ---------------- mean pool over sorted batch (double accumulation) ----------------
#define POOL_CHUNK 64
__global__ __launch_bounds__(128) void pool_kernel(const float* __restrict__ h,
                                                   const int* __restrict__ batch,
                                                   double* __restrict__ psum,
                                                   int* __restrict__ pcnt) {
    int c = threadIdx.x;  // 0..127
    int n0 = blockIdx.x * POOL_CHUNK;
    int n1 = min(n0 + POOL_CHUNK, N_NODES);
    if (n0 >= N_NODES) return;
    double acc = 0.0;
    int cur = batch[n0];
    int cnt = 0;
    for (int n = n0; n < n1; n++) {
        int g = batch[n];
        if (g != cur) {
            atomicAdd(&psum[(size_t)cur * GAT_DIM + c], acc);
            if (c == 0) atomicAdd(&pcnt[cur], cnt);
            acc = 0.0; cnt = 0; cur = g;
        }
        acc += (double)h[(size_t)n * GAT_DIM + c];
        cnt++;
    }
    atomicAdd(&psum[(size_t)cur * GAT_DIM + c], acc);
    if (c == 0) atomicAdd(&pcnt[cur], cnt);
}

// ---------------- final linear: out[64,128] = g @ linW + linb ----------------
__global__ __launch_bounds__(128) void final_kernel(const double* __restrict__ psum,
                                                    const int* __restrict__ pcnt,
                                                    const float* __restrict__ linW,
                                                    const float* __restrict__ linb,
                                                    float* __restrict__ out) {
    int g = blockIdx.x;       // 0..63
    int j = threadIdx.x;      // 0..127
    __shared__ float gv[128];
    float cnt = (float)max(pcnt[g], 1);
    gv[j] = (float)(psum[(size_t)g * 128 + j] / (double)cnt);
    __syncthreads();
    float acc = 0.f;
    for (int c = 0; c < 128; c++) acc = fmaf(gv[c], linW[c * 128 + j], acc);
    out[(size_t)g * 128 + j] = acc + linb[j];
}

extern "C" void kernel_launch(void* const* d_in, const int* in_sizes, int n_in,
                              void* d_out, int out_size, void* d_ws, size_t ws_size,
                              hipStream_t stream) {
    const float* x    = (const float*)d_in[0];
    const int* eidx   = (const int*)d_in[1];
    const int* batch  = (const int*)d_in[2];
    const float* Wl[3] = {(const float*)d_in[3],  (const float*)d_in[9],  (const float*)d_in[15]};
    const float* bl[3] = {(const float*)d_in[4],  (const float*)d_in[10], (const float*)d_in[16]};
    const float* Wr[3] = {(const float*)d_in[5],  (const float*)d_in[11], (const float*)d_in[17]};
    const float* br[3] = {(const float*)d_in[6],  (const float*)d_in[12], (const float*)d_in[18]};
    const float* att[3] = {(const float*)d_in[7], (const float*)d_in[13], (const float*)d_in[19]};
    const float* bb[3] = {(const float*)d_in[8],  (const float*)d_in[14], (const float*)d_in[20]};
    const float* linW = (const float*)d_in[21];
    const float* linb = (const float*)d_in[22];
    float* out = (float*)d_out;

    const int* esrc = eidx;
    const int* edst = eidx + N_EDGES;

    // workspace carve-up (256B aligned)
    char* p = (char*)d_ws;
    auto alloc = [&](size_t bytes) { void* r = (void*)p; p += (bytes + 255) & ~(size_t)255; return r; };
    float* xl      = (float*)alloc((size_t)N_NODES * FDIM * 4);   // 102.4 MB
    float* xr      = (float*)alloc((size_t)N_NODES * FDIM * 4);   // 102.4 MB
    float* hbuf    = (float*)alloc((size_t)N_NODES * GAT_DIM * 4);// 25.6 MB
    int*   off     = (int*)alloc((size_t)(N_NODES + 1) * 4);
    int*   csr_src = (int*)alloc((size_t)N_EDGES * 4);
    // --- contiguous zero region: deg, cursor, psum, pcnt ---
    char* zbase = p;
    int*   deg     = (int*)alloc((size_t)N_NODES * 4);
    int*   cursor  = (int*)alloc((size_t)N_NODES * 4);
    double* psum   = (double*)alloc((size_t)N_GRAPHS * GAT_DIM * 8);
    int*   pcnt    = (int*)alloc((size_t)N_GRAPHS * 4);
    size_t zbytes = (size_t)(p - zbase);

    hipMemsetAsync(zbase, 0, zbytes, stream);

    // CSR build (dst is layer-invariant)
    deg_kernel<<<(N_EDGES + 255) / 256, 256, 0, stream>>>(edst, deg);
    scan_kernel<<<1, 1024, 0, stream>>>(deg, off);
    fill_kernel<<<(N_EDGES + 255) / 256, 256, 0, stream>>>(esrc, edst, off, cursor, csr_src);

    dim3 ggrid(512 / BN, (N_NODES + BM - 1) / BM);
    const int egrid0 = (N_NODES + 3) / 4;   // layer0: 4 nodes per block (1 wave/node)
    const int egrid12 = (N_NODES + 1) / 2;  // layers1/2: 2 nodes per block (2 waves/node)

    // layer 0: fully fused (K=3 transform recomputed per edge)
    fused_edge0_kernel<<<egrid0, 256, 0, stream>>>(off, csr_src, x, Wl[0], bl[0], Wr[0], br[0],
                                                   att[0], bb[0], hbuf);
    // layers 1,2
    for (int l = 1; l < 3; l++) {
        gemm_dual_kernel<<<ggrid, 256, 0, stream>>>(hbuf, Wl[l], bl[l], Wr[l], br[l],
                                                    xl, xr, N_NODES);
        fused_edge_kernel<<<egrid12, 256, 0, stream>>>(off, csr_src, xl, xr, att[l], bb[l], hbuf);
    }

    pool_kernel<<<(N_NODES + POOL_CHUNK - 1) / POOL_CHUNK, 128, 0, stream>>>(hbuf, batch, psum, pcnt);
    final_kernel<<<N_GRAPHS, 128, 0, stream>>>(psum, pcnt, linW, linb, out);
}

// Round 10
// 942.260 us; speedup vs baseline: 6.2974x; 1.0289x over previous
//
#include <hip/hip_runtime.h>
#include <hip/hip_bf16.h>

#define N_NODES 50000
#define N_EDGES 400000
#define N_GRAPHS 64
#define HEADS 4
#define GAT_DIM 128
#define FDIM 512   // HEADS*GAT_DIM
#define NEG_SLOPE 0.2f

// ---------------- CSR build ----------------
__global__ void deg_kernel(const int* __restrict__ edst, int* __restrict__ deg) {
    int e = blockIdx.x * blockDim.x + threadIdx.x;
    if (e < N_EDGES) atomicAdd(&deg[edst[e]], 1);
}

// single block, 1024 threads: exclusive scan of deg[N_NODES] -> off[N_NODES+1]
__global__ __launch_bounds__(1024) void scan_kernel(const int* __restrict__ deg,
                                                    int* __restrict__ off) {
    __shared__ int part[1024];
    const int n = N_NODES;
    int t = threadIdx.x;
    int chunk = (n + 1023) / 1024;
    int base = t * chunk;
    int s = 0;
    for (int i = 0; i < chunk; i++) {
        int idx = base + i;
        if (idx < n) s += deg[idx];
    }
    part[t] = s;
    __syncthreads();
    for (int d = 1; d < 1024; d <<= 1) {
        int add = (t >= d) ? part[t - d] : 0;
        __syncthreads();
        part[t] += add;
        __syncthreads();
    }
    int run = part[t] - s;  // exclusive prefix of this thread's chunk
    for (int i = 0; i < chunk; i++) {
        int idx = base + i;
        if (idx < n) { off[idx] = run; run += deg[idx]; }
    }
    if (t == 0) off[n] = part[1023];
}

__global__ void fill_kernel(const int* __restrict__ esrc, const int* __restrict__ edst,
                            const int* __restrict__ off, int* __restrict__ cursor,
                            int* __restrict__ csr_src) {
    int e = blockIdx.x * blockDim.x + threadIdx.x;
    if (e >= N_EDGES) return;
    int d = edst[e];
    int pos = off[d] + atomicAdd(&cursor[d], 1);
    csr_src[pos] = esrc[e];
}

// ---------------- dual fp32 GEMM (R6 champion: BK=16, single-buffer LDS + reg prefetch) ----
// Measured: 170-174us, VALUBusy ~66%, VGPR 64 — LDS-issue-bound local optimum
// (4 ds_read_b128 per 64 FMA; CU demand/cap = 1.5 -> ~66% VALU cap, measured matches).
// DO NOT: (256,8) -> spills acc (R5, 20GB scratch); B-from-global unrolled -> hoist spills
// (R7, 10GB); wave-column + unroll 1 -> exposed L2 latency, 24% VALU (R8).
#define BM 128
#define BN 64
#define BK 16
#define APAD 132
#define BPAD 68
__global__ __launch_bounds__(256, 4) void gemm_dual_kernel(const float* __restrict__ A,
                                                           const float* __restrict__ Wl,
                                                           const float* __restrict__ bl,
                                                           const float* __restrict__ Wr,
                                                           const float* __restrict__ br,
                                                           float* __restrict__ xl,
                                                           float* __restrict__ xr, int M) {
    __shared__ float As[BK][APAD];
    __shared__ float Bsl[BK][BPAD];
    __shared__ float Bsr[BK][BPAD];
    int bn = blockIdx.x * BN;
    int bm = blockIdx.y * BM;
    int tid = threadIdx.x;
    int tm = tid & 15, tn = tid >> 4;
    float accl[8][4] = {};
    float accr[8][4] = {};

    const int arow[2] = {(tid * 2 + 0) >> 2, (tid * 2 + 1) >> 2};
    const int ac4[2]  = {((tid * 2 + 0) & 3) * 4, ((tid * 2 + 1) & 3) * 4};
    const int brow = tid >> 4;
    const int bc4  = (tid & 15) * 4;

    float4 pa[2], pbl, pbr;

#pragma unroll
    for (int i = 0; i < 2; i++) {
        int gr = bm + arow[i];
        pa[i] = (gr < M) ? *(const float4*)(A + (size_t)gr * 128 + 0 + ac4[i])
                         : make_float4(0.f, 0.f, 0.f, 0.f);
    }
    pbl = *(const float4*)(Wl + (size_t)(0 + brow) * 512 + bn + bc4);
    pbr = *(const float4*)(Wr + (size_t)(0 + brow) * 512 + bn + bc4);
#pragma unroll
    for (int i = 0; i < 2; i++) {
        As[ac4[i] + 0][arow[i]] = pa[i].x; As[ac4[i] + 1][arow[i]] = pa[i].y;
        As[ac4[i] + 2][arow[i]] = pa[i].z; As[ac4[i] + 3][arow[i]] = pa[i].w;
    }
    *(float4*)&Bsl[brow][bc4] = pbl;
    *(float4*)&Bsr[brow][bc4] = pbr;
    __syncthreads();

    for (int s = 0; s < 8; s++) {
        if (s < 7) {
            int k0 = (s + 1) * BK;
#pragma unroll
            for (int i = 0; i < 2; i++) {
                int gr = bm + arow[i];
                pa[i] = (gr < M) ? *(const float4*)(A + (size_t)gr * 128 + k0 + ac4[i])
                                 : make_float4(0.f, 0.f, 0.f, 0.f);
            }
            pbl = *(const float4*)(Wl + (size_t)(k0 + brow) * 512 + bn + bc4);
            pbr = *(const float4*)(Wr + (size_t)(k0 + brow) * 512 + bn + bc4);
        }
#pragma unroll 4
        for (int k = 0; k < BK; k++) {
            float4 alo = *(const float4*)&As[k][tm * 4];
            float4 ahi = *(const float4*)&As[k][64 + tm * 4];
            float4 vbl = *(const float4*)&Bsl[k][tn * 4];
            float4 vbr = *(const float4*)&Bsr[k][tn * 4];
            float av[8] = {alo.x, alo.y, alo.z, alo.w, ahi.x, ahi.y, ahi.z, ahi.w};
            float blv[4] = {vbl.x, vbl.y, vbl.z, vbl.w};
            float brv[4] = {vbr.x, vbr.y, vbr.z, vbr.w};
#pragma unroll
            for (int i = 0; i < 8; i++)
#pragma unroll
                for (int j = 0; j < 4; j++) {
                    accl[i][j] = fmaf(av[i], blv[j], accl[i][j]);
                    accr[i][j] = fmaf(av[i], brv[j], accr[i][j]);
                }
        }
        if (s < 7) {
            __syncthreads();
#pragma unroll
            for (int i = 0; i < 2; i++) {
                As[ac4[i] + 0][arow[i]] = pa[i].x; As[ac4[i] + 1][arow[i]] = pa[i].y;
                As[ac4[i] + 2][arow[i]] = pa[i].z; As[ac4[i] + 3][arow[i]] = pa[i].w;
            }
            *(float4*)&Bsl[brow][bc4] = pbl;
            *(float4*)&Bsr[brow][bc4] = pbr;
            __syncthreads();
        }
    }

    int gc = bn + tn * 4;
    float4 bll = *(const float4*)(bl + gc);
    float4 brr = *(const float4*)(br + gc);
#pragma unroll
    for (int i = 0; i < 8; i++) {
        int gr = bm + (i < 4 ? tm * 4 + i : 64 + tm * 4 + (i - 4));
        if (gr >= M) continue;
        float4 ol, orr;
        ol.x = accl[i][0] + bll.x; ol.y = accl[i][1] + bll.y;
        ol.z = accl[i][2] + bll.z; ol.w = accl[i][3] + bll.w;
        orr.x = accr[i][0] + brr.x; orr.y = accr[i][1] + brr.y;
        orr.z = accr[i][2] + brr.z; orr.w = accr[i][3] + brr.w;
        *(float4*)(xl + (size_t)gr * 512 + gc) = ol;
        *(float4*)(xr + (size_t)gr * 512 + gc) = orr;
    }
}

#define LK(mm) fmaf(fminf(mm, 0.f), NEG_SLOPE, fmaxf(mm, 0.f))

// ------- LAYER 0 fully fused: transform (K=3, per-edge recompute) + score + softmax
//         + aggregate + head-mean + bias + ELU. One wave per node, 2-deep x prefetch.
__global__ __launch_bounds__(256) void fused_edge0_kernel(const int* __restrict__ off,
                                                          const int* __restrict__ csr_src,
                                                          const float* __restrict__ x,
                                                          const float* __restrict__ Wl,
                                                          const float* __restrict__ bl,
                                                          const float* __restrict__ Wr,
                                                          const float* __restrict__ br,
                                                          const float* __restrict__ att,
                                                          const float* __restrict__ bias,
                                                          float* __restrict__ hout) {
    int wid = threadIdx.x >> 6;
    int lane = threadIdx.x & 63;
    int n = blockIdx.x * 4 + wid;
    if (n >= N_NODES) return;
    int s = off[n], e = off[n + 1];
    const int loff = lane * 8;
    float4 wl00 = *(const float4*)(Wl + loff),        wl01 = *(const float4*)(Wl + loff + 4);
    float4 wl10 = *(const float4*)(Wl + 512 + loff),  wl11 = *(const float4*)(Wl + 512 + loff + 4);
    float4 wl20 = *(const float4*)(Wl + 1024 + loff), wl21 = *(const float4*)(Wl + 1024 + loff + 4);
    float4 bl0  = *(const float4*)(bl + loff),        bl1  = *(const float4*)(bl + loff + 4);
    float4 at0  = *(const float4*)(att + loff),       at1  = *(const float4*)(att + loff + 4);
    float xn0 = x[n * 3 + 0], xn1 = x[n * 3 + 1], xn2 = x[n * 3 + 2];
    float4 xr0, xr1;
    {
        float4 wr00 = *(const float4*)(Wr + loff),        wr01 = *(const float4*)(Wr + loff + 4);
        float4 wr10 = *(const float4*)(Wr + 512 + loff),  wr11 = *(const float4*)(Wr + 512 + loff + 4);
        float4 wr20 = *(const float4*)(Wr + 1024 + loff), wr21 = *(const float4*)(Wr + 1024 + loff + 4);
        float4 br0  = *(const float4*)(br + loff),        br1  = *(const float4*)(br + loff + 4);
        xr0.x = fmaf(xn0, wr00.x, fmaf(xn1, wr10.x, fmaf(xn2, wr20.x, br0.x)));
        xr0.y = fmaf(xn0, wr00.y, fmaf(xn1, wr10.y, fmaf(xn2, wr20.y, br0.y)));
        xr0.z = fmaf(xn0, wr00.z, fmaf(xn1, wr10.z, fmaf(xn2, wr20.z, br0.z)));
        xr0.w = fmaf(xn0, wr00.w, fmaf(xn1, wr10.w, fmaf(xn2, wr20.w, br0.w)));
        xr1.x = fmaf(xn0, wr01.x, fmaf(xn1, wr11.x, fmaf(xn2, wr21.x, br1.x)));
        xr1.y = fmaf(xn0, wr01.y, fmaf(xn1, wr11.y, fmaf(xn2, wr21.y, br1.y)));
        xr1.z = fmaf(xn0, wr01.z, fmaf(xn1, wr11.z, fmaf(xn2, wr21.z, br1.z)));
        xr1.w = fmaf(xn0, wr01.w, fmaf(xn1, wr11.w, fmaf(xn2, wr21.w, br1.w)));
    }

    float mx = -1e30f, denom = 0.f;
    float a0 = 0.f, a1 = 0.f, a2 = 0.f, a3 = 0.f, a4 = 0.f, a5 = 0.f, a6 = 0.f, a7 = 0.f;

    float c0, c1, c2, n0, n1, n2;
    if (s < e) { int i0 = csr_src[s]; c0 = x[i0 * 3]; c1 = x[i0 * 3 + 1]; c2 = x[i0 * 3 + 2]; }
    if (s + 1 < e) { int i1 = csr_src[s + 1]; n0 = x[i1 * 3]; n1 = x[i1 * 3 + 1]; n2 = x[i1 * 3 + 2]; }
    for (int p = s; p < e; p++) {
        float t0, t1, t2;
        if (p + 2 < e) {
            int i2 = csr_src[p + 2];
            t0 = x[i2 * 3]; t1 = x[i2 * 3 + 1]; t2 = x[i2 * 3 + 2];
        }
        float4 v0, v1;
        v0.x = fmaf(c0, wl00.x, fmaf(c1, wl10.x, fmaf(c2, wl20.x, bl0.x)));
        v0.y = fmaf(c0, wl00.y, fmaf(c1, wl10.y, fmaf(c2, wl20.y, bl0.y)));
        v0.z = fmaf(c0, wl00.z, fmaf(c1, wl10.z, fmaf(c2, wl20.z, bl0.z)));
        v0.w = fmaf(c0, wl00.w, fmaf(c1, wl10.w, fmaf(c2, wl20.w, bl0.w)));
        v1.x = fmaf(c0, wl01.x, fmaf(c1, wl11.x, fmaf(c2, wl21.x, bl1.x)));
        v1.y = fmaf(c0, wl01.y, fmaf(c1, wl11.y, fmaf(c2, wl21.y, bl1.y)));
        v1.z = fmaf(c0, wl01.z, fmaf(c1, wl11.z, fmaf(c2, wl21.z, bl1.z)));
        v1.w = fmaf(c0, wl01.w, fmaf(c1, wl11.w, fmaf(c2, wl21.w, bl1.w)));
        float part;
        part = LK(v0.x + xr0.x) * at0.x;
        part = fmaf(LK(v0.y + xr0.y), at0.y, part);
        part = fmaf(LK(v0.z + xr0.z), at0.z, part);
        part = fmaf(LK(v0.w + xr0.w), at0.w, part);
        part = fmaf(LK(v1.x + xr1.x), at1.x, part);
        part = fmaf(LK(v1.y + xr1.y), at1.y, part);
        part = fmaf(LK(v1.z + xr1.z), at1.z, part);
        part = fmaf(LK(v1.w + xr1.w), at1.w, part);
        part += __shfl_xor(part, 1);
        part += __shfl_xor(part, 2);
        part += __shfl_xor(part, 4);
        part += __shfl_xor(part, 8);
        float mnew = fmaxf(mx, part);
        float scale = __expf(mx - mnew);
        float w = __expf(part - mnew);
        denom = fmaf(denom, scale, w);
        a0 = fmaf(a0, scale, w * v0.x);
        a1 = fmaf(a1, scale, w * v0.y);
        a2 = fmaf(a2, scale, w * v0.z);
        a3 = fmaf(a3, scale, w * v0.w);
        a4 = fmaf(a4, scale, w * v1.x);
        a5 = fmaf(a5, scale, w * v1.y);
        a6 = fmaf(a6, scale, w * v1.z);
        a7 = fmaf(a7, scale, w * v1.w);
        mx = mnew;
        c0 = n0; c1 = n1; c2 = n2;
        n0 = t0; n1 = t1; n2 = t2;
    }
    float inv = denom > 0.f ? 1.f / denom : 0.f;
    a0 *= inv; a1 *= inv; a2 *= inv; a3 *= inv;
    a4 *= inv; a5 *= inv; a6 *= inv; a7 *= inv;
    a0 += __shfl_xor(a0, 16); a0 += __shfl_xor(a0, 32);
    a1 += __shfl_xor(a1, 16); a1 += __shfl_xor(a1, 32);
    a2 += __shfl_xor(a2, 16); a2 += __shfl_xor(a2, 32);
    a3 += __shfl_xor(a3, 16); a3 += __shfl_xor(a3, 32);
    a4 += __shfl_xor(a4, 16); a4 += __shfl_xor(a4, 32);
    a5 += __shfl_xor(a5, 16); a5 += __shfl_xor(a5, 32);
    a6 += __shfl_xor(a6, 16); a6 += __shfl_xor(a6, 32);
    a7 += __shfl_xor(a7, 16); a7 += __shfl_xor(a7, 32);
    if (lane < 16) {
        float4 b0 = *(const float4*)(bias + lane * 8);
        float4 b1 = *(const float4*)(bias + lane * 8 + 4);
        float o[8];
        o[0] = fmaf(0.25f, a0, b0.x); o[1] = fmaf(0.25f, a1, b0.y);
        o[2] = fmaf(0.25f, a2, b0.z); o[3] = fmaf(0.25f, a3, b0.w);
        o[4] = fmaf(0.25f, a4, b1.x); o[5] = fmaf(0.25f, a5, b1.y);
        o[6] = fmaf(0.25f, a6, b1.z); o[7] = fmaf(0.25f, a7, b1.w);
#pragma unroll
        for (int j = 0; j < 8; j++) o[j] = o[j] > 0.f ? o[j] : (__expf(o[j]) - 1.f);
        *(float4*)(hout + (size_t)n * GAT_DIM + lane * 8) = make_float4(o[0], o[1], o[2], o[3]);
        *(float4*)(hout + (size_t)n * GAT_DIM + lane * 8 + 4) = make_float4(o[4], o[5], o[6], o[7]);
    }
}

// ------- layers 1/2: fused edge (R6 champion form), one wave per node, 2-deep prefetch ----
// R9 showed 2-wave parity split is neutral-to-negative: phase is gather-BW bound, not
// latency-bound — total L2-level gather volume (2KB/edge) is the invariant cost.
__global__ __launch_bounds__(256) void fused_edge_kernel(const int* __restrict__ off,
                                                         const int* __restrict__ csr_src,
                                                         const float* __restrict__ xl,
                                                         const float* __restrict__ xr,
                                                         const float* __restrict__ att,
                                                         const float* __restrict__ bias,
                                                         float* __restrict__ hout) {
    int wid = threadIdx.x >> 6;
    int lane = threadIdx.x & 63;
    int n = blockIdx.x * 4 + wid;
    if (n >= N_NODES) return;
    int s = off[n], e = off[n + 1];
    const int loff = lane * 8;
    float4 xr0 = *(const float4*)(xr + (size_t)n * FDIM + loff);
    float4 xr1 = *(const float4*)(xr + (size_t)n * FDIM + loff + 4);
    float4 at0 = *(const float4*)(att + loff);
    float4 at1 = *(const float4*)(att + loff + 4);

    float mx = -1e30f, denom = 0.f;
    float a0 = 0.f, a1 = 0.f, a2 = 0.f, a3 = 0.f, a4 = 0.f, a5 = 0.f, a6 = 0.f, a7 = 0.f;

    float4 v0, v1, w0, w1;
    if (s < e) {
        const float* b = xl + (size_t)csr_src[s] * FDIM + loff;
        v0 = *(const float4*)b; v1 = *(const float4*)(b + 4);
    }
    if (s + 1 < e) {
        const float* b = xl + (size_t)csr_src[s + 1] * FDIM + loff;
        w0 = *(const float4*)b; w1 = *(const float4*)(b + 4);
    }
    for (int p = s; p < e; p++) {
        float4 t0, t1;
        if (p + 2 < e) {
            const float* b = xl + (size_t)csr_src[p + 2] * FDIM + loff;
            t0 = *(const float4*)b; t1 = *(const float4*)(b + 4);
        }
        float part;
        part = LK(v0.x + xr0.x) * at0.x;
        part = fmaf(LK(v0.y + xr0.y), at0.y, part);
        part = fmaf(LK(v0.z + xr0.z), at0.z, part);
        part = fmaf(LK(v0.w + xr0.w), at0.w, part);
        part = fmaf(LK(v1.x + xr1.x), at1.x, part);
        part = fmaf(LK(v1.y + xr1.y), at1.y, part);
        part = fmaf(LK(v1.z + xr1.z), at1.z, part);
        part = fmaf(LK(v1.w + xr1.w), at1.w, part);
        part += __shfl_xor(part, 1);
        part += __shfl_xor(part, 2);
        part += __shfl_xor(part, 4);
        part += __shfl_xor(part, 8);
        float mnew = fmaxf(mx, part);
        float scale = __expf(mx - mnew);
        float w = __expf(part - mnew);
        denom = fmaf(denom, scale, w);
        a0 = fmaf(a0, scale, w * v0.x);
        a1 = fmaf(a1, scale, w * v0.y);
        a2 = fmaf(a2, scale, w * v0.z);
        a3 = fmaf(a3, scale, w * v0.w);
        a4 = fmaf(a4, scale, w * v1.x);
        a5 = fmaf(a5, scale, w * v1.y);
        a6 = fmaf(a6, scale, w * v1.z);
        a7 = fmaf(a7, scale, w * v1.w);
        mx = mnew;
        v0 = w0; v1 = w1;
        w0 = t0; w1 = t1;
    }
    float inv = denom > 0.f ? 1.f / denom : 0.f;
    a0 *= inv; a1 *= inv; a2 *= inv; a3 *= inv;
    a4 *= inv; a5 *= inv; a6 *= inv; a7 *= inv;
    a0 += __shfl_xor(a0, 16); a0 += __shfl_xor(a0, 32);
    a1 += __shfl_xor(a1, 16); a1 += __shfl_xor(a1, 32);
    a2 += __shfl_xor(a2, 16); a2 += __shfl_xor(a2, 32);
    a3 += __shfl_xor(a3, 16); a3 += __shfl_xor(a3, 32);
    a4 += __shfl_xor(a4, 16); a4 += __shfl_xor(a4, 32);
    a5 += __shfl_xor(a5, 16); a5 += __shfl_xor(a5, 32);
    a6 += __shfl_xor(a6, 16); a6 += __shfl_xor(a6, 32);
    a7 += __shfl_xor(a7, 16); a7 += __shfl_xor(a7, 32);
    if (lane < 16) {
        float4 b0 = *(const float4*)(bias + lane * 8);
        float4 b1 = *(const float4*)(bias + lane * 8 + 4);
        float o[8];
        o[0] = fmaf(0.25f, a0, b0.x); o[1] = fmaf(0.25f, a1, b0.y);
        o[2] = fmaf(0.25f, a2, b0.z); o[3] = fmaf(0.25f, a3, b0.w);
        o[4] = fmaf(0.25f, a4, b1.x); o[5] = fmaf(0.25f, a5, b1.y);
        o[6] = fmaf(0.25f, a6, b1.z); o[7] = fmaf(0.25f, a7, b1.w);
#pragma unroll
        for (int j = 0; j < 8; j++) o[j] = o[j] > 0.f ? o[j] : (__expf(o[j]) - 1.f);
        *(float4*)(hout + (size_t)n * GAT_DIM + lane * 8) = make_float4(o[0], o[1], o[2], o[3]);
        *(float4*)(hout + (size_t)n * GAT_DIM + lane * 8 + 4) = make_float4(o[4], o[5], o[6], o[7]);
    }
}

// ---------------- mean pool over sorted batch (double accumulation) ----------------
#define POOL_CHUNK 64
__global__ __launch_bounds__(128) void pool_kernel(const float* __restrict__ h,
                                                   const int* __restrict__ batch,
                                                   double* __restrict__ psum,
                                                   int* __restrict__ pcnt) {
    int c = threadIdx.x;  // 0..127
    int n0 = blockIdx.x * POOL_CHUNK;
    int n1 = min(n0 + POOL_CHUNK, N_NODES);
    if (n0 >= N_NODES) return;
    double acc = 0.0;
    int cur = batch[n0];
    int cnt = 0;
    for (int n = n0; n < n1; n++) {
        int g = batch[n];
        if (g != cur) {
            atomicAdd(&psum[(size_t)cur * GAT_DIM + c], acc);
            if (c == 0) atomicAdd(&pcnt[cur], cnt);
            acc = 0.0; cnt = 0; cur = g;
        }
        acc += (double)h[(size_t)n * GAT_DIM + c];
        cnt++;
    }
    atomicAdd(&psum[(size_t)cur * GAT_DIM + c], acc);
    if (c == 0) atomicAdd(&pcnt[cur], cnt);
}

// ---------------- final linear: out[64,128] = g @ linW + linb ----------------
__global__ __launch_bounds__(128) void final_kernel(const double* __restrict__ psum,
                                                    const int* __restrict__ pcnt,
                                                    const float* __restrict__ linW,
                                                    const float* __restrict__ linb,
                                                    float* __restrict__ out) {
    int g = blockIdx.x;       // 0..63
    int j = threadIdx.x;      // 0..127
    __shared__ float gv[128];
    float cnt = (float)max(pcnt[g], 1);
    gv[j] = (float)(psum[(size_t)g * 128 + j] / (double)cnt);
    __syncthreads();
    float acc = 0.f;
    for (int c = 0; c < 128; c++) acc = fmaf(gv[c], linW[c * 128 + j], acc);
    out[(size_t)g * 128 + j] = acc + linb[j];
}

extern "C" void kernel_launch(void* const* d_in, const int* in_sizes, int n_in,
                              void* d_out, int out_size, void* d_ws, size_t ws_size,
                              hipStream_t stream) {
    const float* x    = (const float*)d_in[0];
    const int* eidx   = (const int*)d_in[1];
    const int* batch  = (const int*)d_in[2];
    const float* Wl[3] = {(const float*)d_in[3],  (const float*)d_in[9],  (const float*)d_in[15]};
    const float* bl[3] = {(const float*)d_in[4],  (const float*)d_in[10], (const float*)d_in[16]};
    const float* Wr[3] = {(const float*)d_in[5],  (const float*)d_in[11], (const float*)d_in[17]};
    const float* br[3] = {(const float*)d_in[6],  (const float*)d_in[12], (const float*)d_in[18]};
    const float* att[3] = {(const float*)d_in[7], (const float*)d_in[13], (const float*)d_in[19]};
    const float* bb[3] = {(const float*)d_in[8],  (const float*)d_in[14], (const float*)d_in[20]};
    const float* linW = (const float*)d_in[21];
    const float* linb = (const float*)d_in[22];
    float* out = (float*)d_out;

    const int* esrc = eidx;
    const int* edst = eidx + N_EDGES;

    // workspace carve-up (256B aligned)
    char* p = (char*)d_ws;
    auto alloc = [&](size_t bytes) { void* r = (void*)p; p += (bytes + 255) & ~(size_t)255; return r; };
    float* xl      = (float*)alloc((size_t)N_NODES * FDIM * 4);   // 102.4 MB
    float* xr      = (float*)alloc((size_t)N_NODES * FDIM * 4);   // 102.4 MB
    float* hbuf    = (float*)alloc((size_t)N_NODES * GAT_DIM * 4);// 25.6 MB
    int*   off     = (int*)alloc((size_t)(N_NODES + 1) * 4);
    int*   csr_src = (int*)alloc((size_t)N_EDGES * 4);
    // --- contiguous zero region: deg, cursor, psum, pcnt ---
    char* zbase = p;
    int*   deg     = (int*)alloc((size_t)N_NODES * 4);
    int*   cursor  = (int*)alloc((size_t)N_NODES * 4);
    double* psum   = (double*)alloc((size_t)N_GRAPHS * GAT_DIM * 8);
    int*   pcnt    = (int*)alloc((size_t)N_GRAPHS * 4);
    size_t zbytes = (size_t)(p - zbase);

    hipMemsetAsync(zbase, 0, zbytes, stream);

    // CSR build (dst is layer-invariant)
    deg_kernel<<<(N_EDGES + 255) / 256, 256, 0, stream>>>(edst, deg);
    scan_kernel<<<1, 1024, 0, stream>>>(deg, off);
    fill_kernel<<<(N_EDGES + 255) / 256, 256, 0, stream>>>(esrc, edst, off, cursor, csr_src);

    dim3 ggrid(512 / BN, (N_NODES + BM - 1) / BM);
    const int egrid = (N_NODES + 3) / 4;  // 4 nodes (waves) per 256-thr block

    // layer 0: fully fused (K=3 transform recomputed per edge)
    fused_edge0_kernel<<<egrid, 256, 0, stream>>>(off, csr_src, x, Wl[0], bl[0], Wr[0], br[0],
                                                  att[0], bb[0], hbuf);
    // layers 1,2
    for (int l = 1; l < 3; l++) {
        gemm_dual_kernel<<<ggrid, 256, 0, stream>>>(hbuf, Wl[l], bl[l], Wr[l], br[l],
                                                    xl, xr, N_NODES);
        fused_edge_kernel<<<egrid, 256, 0, stream>>>(off, csr_src, xl, xr, att[l], bb[l], hbuf);
    }

    pool_kernel<<<(N_NODES + POOL_CHUNK - 1) / POOL_CHUNK, 128, 0, stream>>>(hbuf, batch, psum, pcnt);
    final_kernel<<<N_GRAPHS, 128, 0, stream>>>(psum, pcnt, linW, linb, out);
}